// Round 2
// baseline (1064.828 us; speedup 1.0000x reference)
//
#include <hip/hip_runtime.h>
#include <cstdint>
#include <cstddef>

#define BB 16
#define NN 512
#define FF 256
#define NC 32
#define KITERS 10
#define CCITERS 20

// ---------------- degree / normalization (double) ----------------
__global__ __launch_bounds__(64) void deg_kernel(const float* __restrict__ adj,
                                                 double* __restrict__ dinv) {
  int i = blockIdx.x, b = blockIdx.y, lane = threadIdx.x;
  const float* row = adj + ((size_t)(b * NN + i)) * NN;
  float s = 0.f;
  for (int q = 0; q < NN; q += 64) s += row[q + lane];  // 0/1 values: exact
  for (int off = 32; off; off >>= 1) s += __shfl_down(s, off, 64);
  if (lane == 0) {
    double tot = (double)s + 1.0;    // a = adj + I
    if (tot < 1.0) tot = 1.0;        // clip(.,1,None)
    dinv[b * NN + i] = 1.0 / sqrt(tot);
  }
}

// ---------------- GEMM: Y[b] = dinv_row * (X[b] @ W), fp64 accumulate ----------------
__global__ __launch_bounds__(256) void gemm_scale(const float* __restrict__ X,
                                                  const float* __restrict__ W,
                                                  const double* __restrict__ dinv,
                                                  float* __restrict__ Y) {
  __shared__ float As[16][68];  // [k][m], padded
  __shared__ float Bs[16][64];  // [k][n]
  int bm = blockIdx.x, bn = blockIdx.y, b = blockIdx.z;
  int tid = threadIdx.x;
  int tx = tid & 15, ty = tid >> 4;
  const float* Xb = X + (size_t)b * NN * FF;
  float* Yb = Y + (size_t)b * NN * FF;
  double acc[4][4] = {};
  for (int kt = 0; kt < FF; kt += 16) {
    {
      int m = tid >> 2, kq = (tid & 3) * 4;
      const float4 v = *(const float4*)&Xb[(size_t)(bm * 64 + m) * FF + kt + kq];
      As[kq + 0][m] = v.x; As[kq + 1][m] = v.y; As[kq + 2][m] = v.z; As[kq + 3][m] = v.w;
    }
    {
      int k = tid >> 4, n4 = (tid & 15) * 4;
      *(float4*)&Bs[k][n4] = *(const float4*)&W[(size_t)(kt + k) * FF + bn * 64 + n4];
    }
    __syncthreads();
#pragma unroll
    for (int k = 0; k < 16; ++k) {
      float4 a = *(const float4*)&As[k][ty * 4];
      float4 bv = *(const float4*)&Bs[k][tx * 4];
      double ax = a.x, ay = a.y, az = a.z, aw = a.w;
      double bx = bv.x, by = bv.y, bz = bv.z, bw = bv.w;
      acc[0][0] += ax * bx; acc[0][1] += ax * by; acc[0][2] += ax * bz; acc[0][3] += ax * bw;
      acc[1][0] += ay * bx; acc[1][1] += ay * by; acc[1][2] += ay * bz; acc[1][3] += ay * bw;
      acc[2][0] += az * bx; acc[2][1] += az * by; acc[2][2] += az * bz; acc[2][3] += az * bw;
      acc[3][0] += aw * bx; acc[3][1] += aw * by; acc[3][2] += aw * bz; acc[3][3] += aw * bw;
    }
    __syncthreads();
  }
#pragma unroll
  for (int i = 0; i < 4; ++i) {
    int row = bm * 64 + ty * 4 + i;
    double di = dinv[b * NN + row];
    float4 v;
    v.x = (float)(di * acc[i][0]); v.y = (float)(di * acc[i][1]);
    v.z = (float)(di * acc[i][2]); v.w = (float)(di * acc[i][3]);
    *(float4*)&Yb[(size_t)row * FF + bn * 64 + tx * 4] = v;
  }
}

// ---------------- SpMV: H = relu(dinv_i * ((adj+I) @ y)_i + bias), fp64 acc ----------------
__global__ __launch_bounds__(256) void spmv_relu(const float* __restrict__ Y,
                                                 const float* __restrict__ adj,
                                                 const double* __restrict__ dinv,
                                                 const float* __restrict__ bias,
                                                 float* __restrict__ H) {
  int i = blockIdx.x, b = blockIdx.y, f = threadIdx.x;
  const float* Yb = Y + (size_t)b * NN * FF;
  const float* arow = adj + ((size_t)(b * NN + i)) * NN;
  double z = (double)Yb[(size_t)i * FF + f];  // +I term (diag of adj is 0)
  for (int j = 0; j < NN; ++j) {
    if (arow[j] != 0.0f) z += (double)Yb[(size_t)j * FF + f];
  }
  double h = dinv[b * NN + i] * z + (double)bias[f];
  H[((size_t)(b * NN + i)) * FF + f] = (h > 0.0) ? (float)h : 0.0f;
}

// ---------------- kmeans init ----------------
__global__ __launch_bounds__(256) void centinit_kernel(const float* __restrict__ pts,
                                                       double* __restrict__ cent,
                                                       double* __restrict__ c2) {
  __shared__ double red[256];
  int k = blockIdx.x, f = threadIdx.x;
  double v = (double)pts[(size_t)k * FF + f];
  cent[k * FF + f] = v;
  red[f] = v * v;
  __syncthreads();
  for (int s = 128; s; s >>= 1) { if (f < s) red[f] += red[f + s]; __syncthreads(); }
  if (f == 0) c2[k] = red[0];
}

__global__ __launch_bounds__(256) void p2_kernel(const float* __restrict__ pts,
                                                 double* __restrict__ p2) {
  __shared__ double red[256];
  int p = blockIdx.x, t = threadIdx.x;
  double v = (double)pts[(size_t)p * FF + t];
  red[t] = v * v;
  __syncthreads();
  for (int s = 128; s; s >>= 1) { if (t < s) red[t] += red[t + s]; __syncthreads(); }
  if (t == 0) p2[p] = red[0];
}

// ---------------- kmeans assign + partial centroid sums (fp64) ----------------
__global__ __launch_bounds__(256) void kmeans_assign(const float* __restrict__ pts,
                                                     const double* __restrict__ cent,
                                                     const double* __restrict__ c2,
                                                     const double* __restrict__ p2,
                                                     int* __restrict__ assignI,
                                                     double* __restrict__ part,
                                                     int* __restrict__ cntp,
                                                     float* __restrict__ conceptsF) {
  __shared__ double cs[32][258];   // centroid rows (later reused as sum accumulators)
  __shared__ float ps[32][260];    // point rows
  __shared__ double d2s[32][33];
  __shared__ int as[32];
  int g = blockIdx.x;  // 256 blocks x 32 points
  int tid = threadIdx.x;
  for (int r = 0; r < 32; ++r) cs[r][tid] = cent[r * FF + tid];
  for (int r = 0; r < 32; ++r) ps[r][tid] = pts[(size_t)(g * 32 + r) * FF + tid];
  __syncthreads();

  int p0 = tid >> 4, c0 = tid & 15;
  double a00 = 0., a01 = 0., a10 = 0., a11 = 0.;
#pragma unroll 4
  for (int k = 0; k < FF; ++k) {
    double pa = (double)ps[p0][k];
    double pb = (double)ps[p0 + 16][k];
    double ca = cs[c0][k];
    double cb = cs[c0 + 16][k];
    a00 += pa * ca; a01 += pa * cb;
    a10 += pb * ca; a11 += pb * cb;
  }
  double pp0 = p2[g * 32 + p0], pp1 = p2[g * 32 + p0 + 16];
  double cc0 = c2[c0], cc1 = c2[c0 + 16];
  d2s[p0][c0]           = (pp0 - 2.0 * a00) + cc0;
  d2s[p0][c0 + 16]      = (pp0 - 2.0 * a01) + cc1;
  d2s[p0 + 16][c0]      = (pp1 - 2.0 * a10) + cc0;
  d2s[p0 + 16][c0 + 16] = (pp1 - 2.0 * a11) + cc1;
  __syncthreads();

  if (tid < 32) {
    double m = d2s[tid][0];
    int idx = 0;
    for (int c = 1; c < 32; ++c) {
      double v = d2s[tid][c];
      if (v < m) { m = v; idx = c; }  // strict < : first-wins like argmin
    }
    as[tid] = idx;
    assignI[g * 32 + tid] = idx;
    if (conceptsF) conceptsF[g * 32 + tid] = (float)idx;
  }
  // reuse cs as fp64 accumulators; cs reads are complete (pre-barrier)
  for (int r = 0; r < 32; ++r) cs[r][tid] = 0.0;
  __syncthreads();
  for (int r = 0; r < 32; ++r) { int s = as[r]; cs[s][tid] += (double)ps[r][tid]; }
  for (int r = 0; r < 32; ++r) part[((size_t)r * 256 + g) * FF + tid] = cs[r][tid];
  if (tid < 32) {
    int c = 0;
    for (int r = 0; r < 32; ++r) c += (as[r] == tid) ? 1 : 0;
    cntp[tid * 256 + g] = c;
  }
}

// ---------------- kmeans centroid update (fp64) ----------------
__global__ __launch_bounds__(256) void kmeans_update(const double* __restrict__ part,
                                                     const int* __restrict__ cntp,
                                                     double* __restrict__ cent,
                                                     double* __restrict__ c2) {
  __shared__ double red[256];
  int k = blockIdx.x, f = threadIdx.x;
  double acc = 0.;
  for (int g = 0; g < 256; ++g) acc += part[((size_t)k * 256 + g) * FF + f];
  int cnt = 0;
  for (int g = 0; g < 256; ++g) cnt += cntp[k * 256 + g];
  double v = (cnt > 0) ? (acc / (double)cnt) : cent[k * FF + f];
  cent[k * FF + f] = v;
  red[f] = v * v;
  __syncthreads();
  for (int s = 128; s; s >>= 1) { if (f < s) red[f] += red[f + s]; __syncthreads(); }
  if (f == 0) c2[k] = red[0];
}

// ---------------- adjacency bitmask (adj_same > 0) ----------------
__global__ __launch_bounds__(64) void build_bits(const float* __restrict__ adj,
                                                 const int* __restrict__ concepts,
                                                 unsigned long long* __restrict__ Abits) {
  int i = blockIdx.x, b = blockIdx.y, lane = threadIdx.x;
  int ci = concepts[b * NN + i];
  const float* arow = adj + ((size_t)(b * NN + i)) * NN;
#pragma unroll
  for (int q = 0; q < 8; ++q) {
    int j = q * 64 + lane;
    bool pred = (arow[j] != 0.0f) && (concepts[b * NN + j] == ci);
    unsigned long long m = __ballot(pred ? 1 : 0);
    if (lane == 0) Abits[((size_t)(b * NN + i)) * 8 + q] = m;
  }
}

// ---------------- connected components (exact 20-iter replica) ----------------
__global__ __launch_bounds__(512) void components_kernel(const unsigned long long* __restrict__ Abits,
                                                         int* __restrict__ comp,
                                                         float* __restrict__ maskF) {
  __shared__ unsigned long long A[512][8];
  __shared__ int lab[512];
  __shared__ int ids[512];
  int b = blockIdx.x, t = threadIdx.x;
  for (int r = 0; r < 8; ++r) {
    int w = t + r * 512;
    A[w >> 3][w & 7] = Abits[(size_t)b * 4096 + w];
  }
  lab[t] = t;
  __syncthreads();
  for (int it = 0; it < CCITERS; ++it) {
    int m = lab[t];
#pragma unroll
    for (int q = 0; q < 8; ++q) {
      unsigned long long bits = A[t][q];
      while (bits) {
        int j = (q << 6) + __builtin_ctzll(bits);
        bits &= bits - 1;
        m = min(m, lab[j]);
      }
    }
    __syncthreads();
    lab[t] = m;
    __syncthreads();
    int a = lab[lab[t]];
    __syncthreads();
    lab[t] = a;
    __syncthreads();
    a = lab[lab[t]];
    __syncthreads();
    lab[t] = a;
    __syncthreads();
  }
  if (t == 0) {
    int run = 0;
    for (int i = 0; i < 512; ++i) { run += (lab[i] == i) ? 1 : 0; ids[i] = run; }
  }
  __syncthreads();
  comp[b * NN + t] = ids[lab[t]];
  maskF[b * NN + t] = (t < ids[511]) ? 1.0f : 0.0f;
}

// ---------------- segment sum x_new ----------------
__global__ __launch_bounds__(256) void xnew_kernel(const float* __restrict__ H,
                                                   const int* __restrict__ comp,
                                                   float* __restrict__ xnew) {
  int i = blockIdx.x, b = blockIdx.y, f = threadIdx.x;
  int s = comp[b * NN + i] - 1;  // assignments >= 1 (all masked true)
  atomicAdd(&xnew[((size_t)(b * NN + s)) * FF + f], H[((size_t)(b * NN + i)) * FF + f]);
}

// ---------------- segment max adj_new (adj in {0,1}) ----------------
__global__ __launch_bounds__(512) void adjnew_kernel(const float* __restrict__ adj,
                                                     const int* __restrict__ comp,
                                                     float* __restrict__ out) {
  int i = blockIdx.x, b = blockIdx.y, j = threadIdx.x;
  float a = adj[((size_t)(b * NN + i)) * NN + j];
  if (a != 0.0f) {
    int si = comp[b * NN + i] - 1;
    int sj = comp[b * NN + j] - 1;
    out[((size_t)b * NN + si) * NN + sj] = 1.0f;  // all writers write 1.0 -> benign race
  }
}

extern "C" void kernel_launch(void* const* d_in, const int* in_sizes, int n_in,
                              void* d_out, int out_size, void* d_ws, size_t ws_size,
                              hipStream_t stream) {
  (void)in_sizes; (void)n_in; (void)out_size; (void)ws_size;
  const float* x   = (const float*)d_in[0];
  const float* adj = (const float*)d_in[1];
  // d_in[2] = mask : all-true, unused
  const float* W1 = (const float*)d_in[3];
  const float* b1 = (const float*)d_in[4];
  const float* W2 = (const float*)d_in[5];
  const float* b2 = (const float*)d_in[6];

  float* out = (float*)d_out;
  float* xnew      = out;                       // 16*512*256 = 2097152
  float* adjnew    = out + 2097152;             // 16*512*512 = 4194304
  float* conceptsF = out + 6291456;             // 8192
  float* hout      = out + 6299648;             // 2097152
  float* maskF     = out + 8396800;             // 8192

  char* ws = (char*)d_ws;
  double* dinv = (double*)(ws + 0);                    // 8192 d   (64 KB)
  float*  y    = (float*)(ws + 65536);                 // 2097152 f (8 MB)
  float*  h1   = (float*)(ws + 8454144);               // 2097152 f (8 MB)
  double* cent = (double*)(ws + 16842752);             // 8192 d   (64 KB)
  double* c2   = (double*)(ws + 16908288);             // 32 d
  double* p2   = (double*)(ws + 16908544);             // 8192 d   (64 KB)
  unsigned long long* Abits = (unsigned long long*)(ws + 16974080);  // 65536 u64 (512 KB)
  int* assignI = (int*)(ws + 17498368);                // 8192 i
  int* cntp    = (int*)(ws + 17531136);                // 8192 i
  int* comp    = (int*)(ws + 17563904);                // 8192 i
  double* part = (double*)adjnew;  // 32*256*256 d = 16 MB, exactly fits adjnew; re-zeroed later

  // zero x_new (empty segments stay 0)
  hipMemsetAsync(xnew, 0, (size_t)2097152 * sizeof(float), stream);

  // GCN layer 1 and 2
  deg_kernel<<<dim3(NN, BB), 64, 0, stream>>>(adj, dinv);
  gemm_scale<<<dim3(8, 4, BB), 256, 0, stream>>>(x, W1, dinv, y);
  spmv_relu<<<dim3(NN, BB), 256, 0, stream>>>(y, adj, dinv, b1, h1);
  gemm_scale<<<dim3(8, 4, BB), 256, 0, stream>>>(h1, W2, dinv, y);
  spmv_relu<<<dim3(NN, BB), 256, 0, stream>>>(y, adj, dinv, b2, hout);

  // kmeans on pts = hout (B*N x F)
  const float* pts = hout;
  centinit_kernel<<<NC, 256, 0, stream>>>(pts, cent, c2);
  p2_kernel<<<BB * NN, 256, 0, stream>>>(pts, p2);
  for (int it = 0; it < KITERS; ++it) {
    kmeans_assign<<<256, 256, 0, stream>>>(pts, cent, c2, p2, assignI, part, cntp, nullptr);
    kmeans_update<<<NC, 256, 0, stream>>>(part, cntp, cent, c2);
  }
  kmeans_assign<<<256, 256, 0, stream>>>(pts, cent, c2, p2, assignI, part, cntp, conceptsF);

  // zero adj_new (it doubled as kmeans scratch)
  hipMemsetAsync(adjnew, 0, (size_t)4194304 * sizeof(float), stream);

  // connected components on concept-filtered adjacency
  build_bits<<<dim3(NN, BB), 64, 0, stream>>>(adj, assignI, Abits);
  components_kernel<<<BB, 512, 0, stream>>>(Abits, comp, maskF);

  // segment reductions
  xnew_kernel<<<dim3(NN, BB), 256, 0, stream>>>(hout, comp, xnew);
  adjnew_kernel<<<dim3(NN, BB), 512, 0, stream>>>(adj, comp, adjnew);
}

// Round 3
// 759.390 us; speedup vs baseline: 1.4022x; 1.4022x over previous
//
#include <hip/hip_runtime.h>
#include <cstdint>
#include <cstddef>

#define BB 16
#define NN 512
#define FF 256
#define NC 32
#define KITERS 10
#define CCITERS 20

// ---------------- adjacency bitmask + degree/normalization ----------------
// bits[q] bit j = (adj[i][q*64+j] != 0); degree via popcount (exact integer,
// identical to float sum of 0/1 values).
__global__ __launch_bounds__(64) void build_adjbits(const float* __restrict__ adj,
                                                    unsigned long long* __restrict__ adjbits,
                                                    double* __restrict__ dinv) {
  int i = blockIdx.x, b = blockIdx.y, lane = threadIdx.x;
  const float* row = adj + ((size_t)(b * NN + i)) * NN;
  int deg = 0;
#pragma unroll
  for (int q = 0; q < 8; ++q) {
    bool pred = (row[q * 64 + lane] != 0.0f);
    unsigned long long m = __ballot(pred ? 1 : 0);
    if (lane == 0) {
      adjbits[((size_t)(b * NN + i)) * 8 + q] = m;
      deg += __popcll(m);
    }
  }
  if (lane == 0) {
    double tot = (double)deg + 1.0;  // a = adj + I
    if (tot < 1.0) tot = 1.0;        // clip(.,1,None)
    dinv[b * NN + i] = 1.0 / sqrt(tot);
  }
}

// ---------------- GEMM: Y[b] = dinv_row * (X[b] @ W), fp64 accumulate ----------------
__global__ __launch_bounds__(256) void gemm_scale(const float* __restrict__ X,
                                                  const float* __restrict__ W,
                                                  const double* __restrict__ dinv,
                                                  float* __restrict__ Y) {
  __shared__ float As[16][68];  // [k][m], padded
  __shared__ float Bs[16][64];  // [k][n]
  int bm = blockIdx.x, bn = blockIdx.y, b = blockIdx.z;
  int tid = threadIdx.x;
  int tx = tid & 15, ty = tid >> 4;
  const float* Xb = X + (size_t)b * NN * FF;
  float* Yb = Y + (size_t)b * NN * FF;
  double acc[4][4] = {};
  for (int kt = 0; kt < FF; kt += 16) {
    {
      int m = tid >> 2, kq = (tid & 3) * 4;
      const float4 v = *(const float4*)&Xb[(size_t)(bm * 64 + m) * FF + kt + kq];
      As[kq + 0][m] = v.x; As[kq + 1][m] = v.y; As[kq + 2][m] = v.z; As[kq + 3][m] = v.w;
    }
    {
      int k = tid >> 4, n4 = (tid & 15) * 4;
      *(float4*)&Bs[k][n4] = *(const float4*)&W[(size_t)(kt + k) * FF + bn * 64 + n4];
    }
    __syncthreads();
#pragma unroll
    for (int k = 0; k < 16; ++k) {
      float4 a = *(const float4*)&As[k][ty * 4];
      float4 bv = *(const float4*)&Bs[k][tx * 4];
      double ax = a.x, ay = a.y, az = a.z, aw = a.w;
      double bx = bv.x, by = bv.y, bz = bv.z, bw = bv.w;
      acc[0][0] += ax * bx; acc[0][1] += ax * by; acc[0][2] += ax * bz; acc[0][3] += ax * bw;
      acc[1][0] += ay * bx; acc[1][1] += ay * by; acc[1][2] += ay * bz; acc[1][3] += ay * bw;
      acc[2][0] += az * bx; acc[2][1] += az * by; acc[2][2] += az * bz; acc[2][3] += az * bw;
      acc[3][0] += aw * bx; acc[3][1] += aw * by; acc[3][2] += aw * bz; acc[3][3] += aw * bw;
    }
    __syncthreads();
  }
#pragma unroll
  for (int i = 0; i < 4; ++i) {
    int row = bm * 64 + ty * 4 + i;
    double di = dinv[b * NN + row];
    float4 v;
    v.x = (float)(di * acc[i][0]); v.y = (float)(di * acc[i][1]);
    v.z = (float)(di * acc[i][2]); v.w = (float)(di * acc[i][3]);
    *(float4*)&Yb[(size_t)row * FF + bn * 64 + tx * 4] = v;
  }
}

// ---------------- SpMV via bitmask: H = relu(dinv_i * ((adj+I)@y)_i + bias) ----------------
// Same summation order as the dense scan (ascending j) -> numerically identical.
__global__ __launch_bounds__(256) void spmv_relu(const float* __restrict__ Y,
                                                 const unsigned long long* __restrict__ adjbits,
                                                 const double* __restrict__ dinv,
                                                 const float* __restrict__ bias,
                                                 float* __restrict__ H) {
  int i = blockIdx.x, b = blockIdx.y, f = threadIdx.x;
  const float* Yb = Y + (size_t)b * NN * FF;
  const unsigned long long* brow = adjbits + ((size_t)(b * NN + i)) * 8;
  double z = (double)Yb[(size_t)i * FF + f];  // +I term (diag of adj is 0)
#pragma unroll
  for (int q = 0; q < 8; ++q) {
    unsigned long long bits = brow[q];
    while (bits) {
      int j = (q << 6) + __builtin_ctzll(bits);
      bits &= bits - 1;
      z += (double)Yb[(size_t)j * FF + f];
    }
  }
  double h = dinv[b * NN + i] * z + (double)bias[f];
  H[((size_t)(b * NN + i)) * FF + f] = (h > 0.0) ? (float)h : 0.0f;
}

// ---------------- kmeans init ----------------
__global__ __launch_bounds__(256) void centinit_kernel(const float* __restrict__ pts,
                                                       double* __restrict__ cent,
                                                       double* __restrict__ c2) {
  __shared__ double red[256];
  int k = blockIdx.x, f = threadIdx.x;
  double v = (double)pts[(size_t)k * FF + f];
  cent[k * FF + f] = v;
  red[f] = v * v;
  __syncthreads();
  for (int s = 128; s; s >>= 1) { if (f < s) red[f] += red[f + s]; __syncthreads(); }
  if (f == 0) c2[k] = red[0];
}

__global__ __launch_bounds__(256) void p2_kernel(const float* __restrict__ pts,
                                                 double* __restrict__ p2) {
  __shared__ double red[256];
  int p = blockIdx.x, t = threadIdx.x;
  double v = (double)pts[(size_t)p * FF + t];
  red[t] = v * v;
  __syncthreads();
  for (int s = 128; s; s >>= 1) { if (t < s) red[t] += red[t + s]; __syncthreads(); }
  if (t == 0) p2[p] = red[0];
}

// ---------------- kmeans assign + partial centroid sums (fp64) ----------------
__global__ __launch_bounds__(256) void kmeans_assign(const float* __restrict__ pts,
                                                     const double* __restrict__ cent,
                                                     const double* __restrict__ c2,
                                                     const double* __restrict__ p2,
                                                     int* __restrict__ assignI,
                                                     double* __restrict__ part,
                                                     int* __restrict__ cntp,
                                                     float* __restrict__ conceptsF) {
  __shared__ double cs[32][258];   // centroid rows (later reused as sum accumulators)
  __shared__ float ps[32][260];    // point rows
  __shared__ double d2s[32][33];
  __shared__ int as[32];
  int g = blockIdx.x;  // 256 blocks x 32 points
  int tid = threadIdx.x;
  for (int r = 0; r < 32; ++r) cs[r][tid] = cent[r * FF + tid];
  for (int r = 0; r < 32; ++r) ps[r][tid] = pts[(size_t)(g * 32 + r) * FF + tid];
  __syncthreads();

  int p0 = tid >> 4, c0 = tid & 15;
  double a00 = 0., a01 = 0., a10 = 0., a11 = 0.;
#pragma unroll 4
  for (int k = 0; k < FF; ++k) {
    double pa = (double)ps[p0][k];
    double pb = (double)ps[p0 + 16][k];
    double ca = cs[c0][k];
    double cb = cs[c0 + 16][k];
    a00 += pa * ca; a01 += pa * cb;
    a10 += pb * ca; a11 += pb * cb;
  }
  double pp0 = p2[g * 32 + p0], pp1 = p2[g * 32 + p0 + 16];
  double cc0 = c2[c0], cc1 = c2[c0 + 16];
  d2s[p0][c0]           = (pp0 - 2.0 * a00) + cc0;
  d2s[p0][c0 + 16]      = (pp0 - 2.0 * a01) + cc1;
  d2s[p0 + 16][c0]      = (pp1 - 2.0 * a10) + cc0;
  d2s[p0 + 16][c0 + 16] = (pp1 - 2.0 * a11) + cc1;
  __syncthreads();

  if (tid < 32) {
    double m = d2s[tid][0];
    int idx = 0;
    for (int c = 1; c < 32; ++c) {
      double v = d2s[tid][c];
      if (v < m) { m = v; idx = c; }  // strict < : first-wins like argmin
    }
    as[tid] = idx;
    assignI[g * 32 + tid] = idx;
    if (conceptsF) conceptsF[g * 32 + tid] = (float)idx;
  }
  // reuse cs as fp64 accumulators; cs reads are complete (pre-barrier)
  for (int r = 0; r < 32; ++r) cs[r][tid] = 0.0;
  __syncthreads();
  for (int r = 0; r < 32; ++r) { int s = as[r]; cs[s][tid] += (double)ps[r][tid]; }
  for (int r = 0; r < 32; ++r) part[((size_t)r * 256 + g) * FF + tid] = cs[r][tid];
  if (tid < 32) {
    int c = 0;
    for (int r = 0; r < 32; ++r) c += (as[r] == tid) ? 1 : 0;
    cntp[tid * 256 + g] = c;
  }
}

// ---------------- kmeans centroid update (fp64) ----------------
__global__ __launch_bounds__(256) void kmeans_update(const double* __restrict__ part,
                                                     const int* __restrict__ cntp,
                                                     double* __restrict__ cent,
                                                     double* __restrict__ c2) {
  __shared__ double red[256];
  int k = blockIdx.x, f = threadIdx.x;
  double acc = 0.;
  for (int g = 0; g < 256; ++g) acc += part[((size_t)k * 256 + g) * FF + f];
  int cnt = 0;
  for (int g = 0; g < 256; ++g) cnt += cntp[k * 256 + g];
  double v = (cnt > 0) ? (acc / (double)cnt) : cent[k * FF + f];
  cent[k * FF + f] = v;
  red[f] = v * v;
  __syncthreads();
  for (int s = 128; s; s >>= 1) { if (f < s) red[f] += red[f + s]; __syncthreads(); }
  if (f == 0) c2[k] = red[0];
}

// ---------------- adjacency bitmask filtered by concepts (adj_same > 0) ----------------
__global__ __launch_bounds__(64) void build_bits(const float* __restrict__ adj,
                                                 const int* __restrict__ concepts,
                                                 unsigned long long* __restrict__ Abits) {
  int i = blockIdx.x, b = blockIdx.y, lane = threadIdx.x;
  int ci = concepts[b * NN + i];
  const float* arow = adj + ((size_t)(b * NN + i)) * NN;
#pragma unroll
  for (int q = 0; q < 8; ++q) {
    int j = q * 64 + lane;
    bool pred = (arow[j] != 0.0f) && (concepts[b * NN + j] == ci);
    unsigned long long m = __ballot(pred ? 1 : 0);
    if (lane == 0) Abits[((size_t)(b * NN + i)) * 8 + q] = m;
  }
}

// ---------------- connected components (exact 20-iter replica) ----------------
__global__ __launch_bounds__(512) void components_kernel(const unsigned long long* __restrict__ Abits,
                                                         int* __restrict__ comp,
                                                         float* __restrict__ maskF) {
  __shared__ unsigned long long A[512][8];
  __shared__ int lab[512];
  __shared__ int ids[512];
  int b = blockIdx.x, t = threadIdx.x;
  for (int r = 0; r < 8; ++r) {
    int w = t + r * 512;
    A[w >> 3][w & 7] = Abits[(size_t)b * 4096 + w];
  }
  lab[t] = t;
  __syncthreads();
  for (int it = 0; it < CCITERS; ++it) {
    int m = lab[t];
#pragma unroll
    for (int q = 0; q < 8; ++q) {
      unsigned long long bits = A[t][q];
      while (bits) {
        int j = (q << 6) + __builtin_ctzll(bits);
        bits &= bits - 1;
        m = min(m, lab[j]);
      }
    }
    __syncthreads();
    lab[t] = m;
    __syncthreads();
    int a = lab[lab[t]];
    __syncthreads();
    lab[t] = a;
    __syncthreads();
    a = lab[lab[t]];
    __syncthreads();
    lab[t] = a;
    __syncthreads();
  }
  if (t == 0) {
    int run = 0;
    for (int i = 0; i < 512; ++i) { run += (lab[i] == i) ? 1 : 0; ids[i] = run; }
  }
  __syncthreads();
  comp[b * NN + t] = ids[lab[t]];
  maskF[b * NN + t] = (t < ids[511]) ? 1.0f : 0.0f;
}

// ---------------- segment sum x_new ----------------
__global__ __launch_bounds__(256) void xnew_kernel(const float* __restrict__ H,
                                                   const int* __restrict__ comp,
                                                   float* __restrict__ xnew) {
  int i = blockIdx.x, b = blockIdx.y, f = threadIdx.x;
  int s = comp[b * NN + i] - 1;  // assignments >= 1 (all masked true)
  atomicAdd(&xnew[((size_t)(b * NN + s)) * FF + f], H[((size_t)(b * NN + i)) * FF + f]);
}

// ---------------- segment max adj_new (adj in {0,1}) ----------------
__global__ __launch_bounds__(512) void adjnew_kernel(const float* __restrict__ adj,
                                                     const int* __restrict__ comp,
                                                     float* __restrict__ out) {
  int i = blockIdx.x, b = blockIdx.y, j = threadIdx.x;
  float a = adj[((size_t)(b * NN + i)) * NN + j];
  if (a != 0.0f) {
    int si = comp[b * NN + i] - 1;
    int sj = comp[b * NN + j] - 1;
    out[((size_t)b * NN + si) * NN + sj] = 1.0f;  // all writers write 1.0 -> benign race
  }
}

extern "C" void kernel_launch(void* const* d_in, const int* in_sizes, int n_in,
                              void* d_out, int out_size, void* d_ws, size_t ws_size,
                              hipStream_t stream) {
  (void)in_sizes; (void)n_in; (void)out_size; (void)ws_size;
  const float* x   = (const float*)d_in[0];
  const float* adj = (const float*)d_in[1];
  // d_in[2] = mask : all-true, unused
  const float* W1 = (const float*)d_in[3];
  const float* b1 = (const float*)d_in[4];
  const float* W2 = (const float*)d_in[5];
  const float* b2 = (const float*)d_in[6];

  float* out = (float*)d_out;
  float* xnew      = out;                       // 16*512*256 = 2097152
  float* adjnew    = out + 2097152;             // 16*512*512 = 4194304
  float* conceptsF = out + 6291456;             // 8192
  float* hout      = out + 6299648;             // 2097152
  float* maskF     = out + 8396800;             // 8192

  char* ws = (char*)d_ws;
  double* dinv = (double*)(ws + 0);                    // 8192 d   (64 KB)
  float*  y    = (float*)(ws + 65536);                 // 2097152 f (8 MB)
  float*  h1   = (float*)(ws + 8454144);               // 2097152 f (8 MB)
  double* cent = (double*)(ws + 16842752);             // 8192 d   (64 KB)
  double* c2   = (double*)(ws + 16908288);             // 32 d
  double* p2   = (double*)(ws + 16908544);             // 8192 d   (64 KB)
  unsigned long long* Abits = (unsigned long long*)(ws + 16974080);  // 65536 u64 (512 KB)
  int* assignI = (int*)(ws + 17498368);                // 8192 i
  int* cntp    = (int*)(ws + 17531136);                // 8192 i
  int* comp    = (int*)(ws + 17563904);                // 8192 i
  double* part = (double*)adjnew;  // 32*256*256 d = 16 MB inside adjnew output; re-zeroed later
  unsigned long long* adjbits = (unsigned long long*)xnew;  // 512 KB inside xnew output; done before memset

  // adjacency bits + degree normalization (one pass over adj)
  build_adjbits<<<dim3(NN, BB), 64, 0, stream>>>(adj, adjbits, dinv);

  // GCN layer 1 and 2
  gemm_scale<<<dim3(8, 4, BB), 256, 0, stream>>>(x, W1, dinv, y);
  spmv_relu<<<dim3(NN, BB), 256, 0, stream>>>(y, adjbits, dinv, b1, h1);
  gemm_scale<<<dim3(8, 4, BB), 256, 0, stream>>>(h1, W2, dinv, y);
  spmv_relu<<<dim3(NN, BB), 256, 0, stream>>>(y, adjbits, dinv, b2, hout);

  // kmeans on pts = hout (B*N x F)
  const float* pts = hout;
  centinit_kernel<<<NC, 256, 0, stream>>>(pts, cent, c2);
  p2_kernel<<<BB * NN, 256, 0, stream>>>(pts, p2);
  for (int it = 0; it < KITERS; ++it) {
    kmeans_assign<<<256, 256, 0, stream>>>(pts, cent, c2, p2, assignI, part, cntp, nullptr);
    kmeans_update<<<NC, 256, 0, stream>>>(part, cntp, cent, c2);
  }
  kmeans_assign<<<256, 256, 0, stream>>>(pts, cent, c2, p2, assignI, part, cntp, conceptsF);

  // zero x_new (adjbits scratch no longer needed) and adj_new (kmeans scratch)
  hipMemsetAsync(xnew, 0, (size_t)2097152 * sizeof(float), stream);
  hipMemsetAsync(adjnew, 0, (size_t)4194304 * sizeof(float), stream);

  // connected components on concept-filtered adjacency
  build_bits<<<dim3(NN, BB), 64, 0, stream>>>(adj, assignI, Abits);
  components_kernel<<<BB, 512, 0, stream>>>(Abits, comp, maskF);

  // segment reductions
  xnew_kernel<<<dim3(NN, BB), 256, 0, stream>>>(hout, comp, xnew);
  adjnew_kernel<<<dim3(NN, BB), 512, 0, stream>>>(adj, comp, adjnew);
}

// Round 5
// 695.405 us; speedup vs baseline: 1.5312x; 1.0920x over previous
//
#include <hip/hip_runtime.h>
#include <cstdint>
#include <cstddef>

#define BB 16
#define NN 512
#define FF 256
#define NC 32
#define KITERS 10
#define CCITERS 20
#define MAXD 96    // cap for full-adjacency neighbor list (mean deg ~20)
#define FMAXD 64   // cap for same-concept filtered list

typedef __attribute__((ext_vector_type(4))) double double4_t;

// ---------- adjacency bits + neighbor list + degree normalization ----------
__global__ __launch_bounds__(64) void build_adjbits(const float* __restrict__ adj,
                                                    unsigned long long* __restrict__ adjbits,
                                                    double* __restrict__ dinv,
                                                    unsigned short* __restrict__ nbr,
                                                    int* __restrict__ degv) {
  int i = blockIdx.x, b = blockIdx.y, lane = threadIdx.x;
  const float* row = adj + ((size_t)(b * NN + i)) * NN;
  unsigned long long lmask = (1ULL << lane) - 1ULL;
  int base = 0;
#pragma unroll
  for (int q = 0; q < 8; ++q) {
    bool pred = (row[q * 64 + lane] != 0.0f);
    unsigned long long m = __ballot(pred ? 1 : 0);
    if (lane == 0) adjbits[((size_t)(b * NN + i)) * 8 + q] = m;
    if (pred) {
      int pos = base + __popcll(m & lmask);
      if (pos < MAXD) nbr[((size_t)(b * NN + i)) * MAXD + pos] = (unsigned short)(q * 64 + lane);
    }
    base += __popcll(m);
  }
  if (lane == 0) {
    degv[b * NN + i] = base;
    double tot = (double)base + 1.0;  // a = adj + I; clip no-op since >=1
    dinv[b * NN + i] = 1.0 / sqrt(tot);
  }
}

// ---------- GEMM: Y[b] = dinv_row * (X[b] @ W), fp64 accumulate ----------
__global__ __launch_bounds__(256) void gemm_scale(const float* __restrict__ X,
                                                  const float* __restrict__ W,
                                                  const double* __restrict__ dinv,
                                                  float* __restrict__ Y) {
  __shared__ float As[16][68];
  __shared__ float Bs[16][64];
  int bm = blockIdx.x, bn = blockIdx.y, b = blockIdx.z;
  int tid = threadIdx.x;
  int tx = tid & 15, ty = tid >> 4;
  const float* Xb = X + (size_t)b * NN * FF;
  float* Yb = Y + (size_t)b * NN * FF;
  double acc[4][4] = {};
  for (int kt = 0; kt < FF; kt += 16) {
    {
      int m = tid >> 2, kq = (tid & 3) * 4;
      const float4 v = *(const float4*)&Xb[(size_t)(bm * 64 + m) * FF + kt + kq];
      As[kq + 0][m] = v.x; As[kq + 1][m] = v.y; As[kq + 2][m] = v.z; As[kq + 3][m] = v.w;
    }
    {
      int k = tid >> 4, n4 = (tid & 15) * 4;
      *(float4*)&Bs[k][n4] = *(const float4*)&W[(size_t)(kt + k) * FF + bn * 64 + n4];
    }
    __syncthreads();
#pragma unroll
    for (int k = 0; k < 16; ++k) {
      float4 a = *(const float4*)&As[k][ty * 4];
      float4 bv = *(const float4*)&Bs[k][tx * 4];
      double ax = a.x, ay = a.y, az = a.z, aw = a.w;
      double bx = bv.x, by = bv.y, bz = bv.z, bw = bv.w;
      acc[0][0] += ax * bx; acc[0][1] += ax * by; acc[0][2] += ax * bz; acc[0][3] += ax * bw;
      acc[1][0] += ay * bx; acc[1][1] += ay * by; acc[1][2] += ay * bz; acc[1][3] += ay * bw;
      acc[2][0] += az * bx; acc[2][1] += az * by; acc[2][2] += az * bz; acc[2][3] += az * bw;
      acc[3][0] += aw * bx; acc[3][1] += aw * by; acc[3][2] += aw * bz; acc[3][3] += aw * bw;
    }
    __syncthreads();
  }
#pragma unroll
  for (int i = 0; i < 4; ++i) {
    int row = bm * 64 + ty * 4 + i;
    double di = dinv[b * NN + row];
    float4 v;
    v.x = (float)(di * acc[i][0]); v.y = (float)(di * acc[i][1]);
    v.z = (float)(di * acc[i][2]); v.w = (float)(di * acc[i][3]);
    *(float4*)&Yb[(size_t)row * FF + bn * 64 + tx * 4] = v;
  }
}

// ---------- SpMV via neighbor list: H = relu(dinv_i*((adj+I)@y)_i + bias) ----------
__global__ __launch_bounds__(256) void spmv_relu(const float* __restrict__ Y,
                                                 const unsigned short* __restrict__ nbr,
                                                 const int* __restrict__ degv,
                                                 const unsigned long long* __restrict__ adjbits,
                                                 const double* __restrict__ dinv,
                                                 const float* __restrict__ bias,
                                                 float* __restrict__ H) {
  int i = blockIdx.x, b = blockIdx.y, f = threadIdx.x;
  int row = b * NN + i;
  const float* Yb = Y + (size_t)b * NN * FF;
  double z = (double)Yb[(size_t)i * FF + f];  // +I term
  int deg = degv[row];
  if (deg <= MAXD) {
    const unsigned short* lst = nbr + (size_t)row * MAXD;
    int n = 0;
    for (; n + 4 <= deg; n += 4) {
      int j0 = lst[n], j1 = lst[n + 1], j2 = lst[n + 2], j3 = lst[n + 3];
      float v0 = Yb[(size_t)j0 * FF + f];
      float v1 = Yb[(size_t)j1 * FF + f];
      float v2 = Yb[(size_t)j2 * FF + f];
      float v3 = Yb[(size_t)j3 * FF + f];
      z += (double)v0; z += (double)v1; z += (double)v2; z += (double)v3;
    }
    for (; n < deg; ++n) z += (double)Yb[(size_t)lst[n] * FF + f];
  } else {
    const unsigned long long* brow = adjbits + (size_t)row * 8;
    for (int q = 0; q < 8; ++q) {
      unsigned long long bits = brow[q];
      while (bits) {
        int j = (q << 6) + __builtin_ctzll(bits);
        bits &= bits - 1;
        z += (double)Yb[(size_t)j * FF + f];
      }
    }
  }
  double h = dinv[row] * z + (double)bias[f];
  H[((size_t)row) * FF + f] = (h > 0.0) ? (float)h : 0.0f;
}

// ---------- p2 for all points + centroid init (first 32 rows) ----------
__global__ __launch_bounds__(256) void p2cent_kernel(const float* __restrict__ pts,
                                                     double* __restrict__ p2,
                                                     double* __restrict__ cent,
                                                     double* __restrict__ c2) {
  __shared__ double red[256];
  int p = blockIdx.x, t = threadIdx.x;
  double v = (double)pts[(size_t)p * FF + t];
  if (p < NC) cent[p * FF + t] = v;
  red[t] = v * v;
  __syncthreads();
  for (int s = 128; s; s >>= 1) { if (t < s) red[t] += red[t + s]; __syncthreads(); }
  if (t == 0) {
    p2[p] = red[0];
    if (p < NC) c2[p] = red[0];
  }
}

// ---------- kmeans assign: fp64 MFMA d2 with layout self-identification ----------
__global__ __launch_bounds__(256) void kmeans_assign(const float* __restrict__ pts,
                                                     const double* __restrict__ cent,
                                                     const double* __restrict__ c2,
                                                     const double* __restrict__ p2,
                                                     int* __restrict__ assignI,
                                                     double* __restrict__ part,
                                                     int* __restrict__ cntp,
                                                     float* __restrict__ conceptsF) {
  __shared__ float ps[32][260];      // point rows (fp32)
  __shared__ double csT[256][35];    // csT[k][c] (fp64), reused as acc[32][258]
  __shared__ double d2s[32][33];
  __shared__ double want[3];         // scalar ref dots: (p0,c0),(p0,c1),(p1,c0)
  __shared__ double probe_raw[2][2]; // wave0 lanes 0/1: acc[0],acc[1]
  __shared__ int as[32];
  __shared__ int hyp;                // 0=H1, 1=H2(transposed), 2=scalar fallback
  int g = blockIdx.x, tid = threadIdx.x;

  for (int r = 0; r < 32; ++r) ps[r][tid] = pts[(size_t)(g * 32 + r) * FF + tid];
  for (int rep = 0; rep < 32; ++rep) csT[tid][rep] = cent[rep * FF + tid];
  __syncthreads();

  // 4 waves, each a 16x16 fp64 tile of dots = pts_tile . cent_tileT
  int lane = tid & 63, w = tid >> 6;
  int prow = (w >> 1) * 16, ccol = (w & 1) * 16;
  int r16 = lane & 15, kg = lane >> 4;
  double4_t acc = {0.0, 0.0, 0.0, 0.0};
  for (int kt = 0; kt < FF; kt += 4) {
    double a = (double)ps[prow + r16][kt + kg];
    double bv = csT[kt + kg][ccol + r16];
    acc = __builtin_amdgcn_mfma_f64_16x16x4f64(a, bv, acc, 0, 0, 0);
  }
  if (tid < 2) { probe_raw[tid][0] = acc[0]; probe_raw[tid][1] = acc[1]; }
  __syncthreads();

  // asymmetric reference probes (3 waves, one dot each)
  if (tid < 192) {
    int pw = tid >> 6;                  // 0:(0,0) 1:(0,1) 2:(1,0)
    int pr = (pw == 2) ? 1 : 0;
    int pc = (pw == 1) ? 1 : 0;
    double partial = 0.0;
#pragma unroll
    for (int kk = 0; kk < 4; ++kk)
      partial += (double)ps[pr][lane * 4 + kk] * csT[lane * 4 + kk][pc];
    for (int off = 32; off; off >>= 1) partial += __shfl_xor(partial, off, 64);
    if (lane == 0) want[pw] = partial;
  }
  __syncthreads();
  if (tid == 0) {
    double w00 = want[0], w01 = want[1], w10 = want[2];
    double m00 = probe_raw[0][0], mA = probe_raw[1][0], mB = probe_raw[0][1];
    // H1: D[row=kg*4+reg][col=r16]  -> (m00, mA, mB) == (w00, w01, w10)
    // H2: D[row=r16][col=kg*4+reg]  -> (m00, mB, mA) == (w00, w01, w10)
    auto near = [](double a, double b) { return fabs(a - b) <= 1e-9 * (1.0 + fabs(b)); };
    bool ok00 = near(m00, w00);
    bool h1 = ok00 && near(mA, w01) && near(mB, w10);
    bool h2 = ok00 && near(mB, w01) && near(mA, w10);
    hyp = h1 ? 0 : (h2 ? 1 : 2);
  }
  __syncthreads();
  int hh = hyp;
  if (hh == 0) {
#pragma unroll
    for (int ii = 0; ii < 4; ++ii) {
      int row = prow + kg * 4 + ii, col = ccol + r16;
      d2s[row][col] = (p2[g * 32 + row] - 2.0 * acc[ii]) + c2[col];
    }
  } else if (hh == 1) {
#pragma unroll
    for (int ii = 0; ii < 4; ++ii) {
      int row = prow + r16, col = ccol + kg * 4 + ii;
      d2s[row][col] = (p2[g * 32 + row] - 2.0 * acc[ii]) + c2[col];
    }
  }
  __syncthreads();
  if (hh == 2) {  // proven scalar fallback (block-uniform)
    int p0 = tid >> 4, c0 = tid & 15;
    double a00 = 0., a01 = 0., a10 = 0., a11 = 0.;
    for (int k = 0; k < FF; ++k) {
      double pa = (double)ps[p0][k], pb = (double)ps[p0 + 16][k];
      double ca = csT[k][c0], cb = csT[k][c0 + 16];
      a00 += pa * ca; a01 += pa * cb; a10 += pb * ca; a11 += pb * cb;
    }
    double pp0 = p2[g * 32 + p0], pp1 = p2[g * 32 + p0 + 16];
    double cc0 = c2[c0], cc1 = c2[c0 + 16];
    d2s[p0][c0]           = (pp0 - 2.0 * a00) + cc0;
    d2s[p0][c0 + 16]      = (pp0 - 2.0 * a01) + cc1;
    d2s[p0 + 16][c0]      = (pp1 - 2.0 * a10) + cc0;
    d2s[p0 + 16][c0 + 16] = (pp1 - 2.0 * a11) + cc1;
  }
  __syncthreads();

  if (tid < 32) {
    double m = d2s[tid][0];
    int idx = 0;
    for (int c = 1; c < 32; ++c) {
      double v = d2s[tid][c];
      if (v < m) { m = v; idx = c; }  // strict <: first-wins like argmin
    }
    as[tid] = idx;
    assignI[g * 32 + tid] = idx;
    if (conceptsF) conceptsF[g * 32 + tid] = (float)idx;
  }
  // reuse csT storage as fp64 accumulators acc[32][258] (all csT reads done)
  double* accm = &csT[0][0];
  for (int r = 0; r < 32; ++r) accm[r * 258 + tid] = 0.0;
  __syncthreads();
  for (int r = 0; r < 32; ++r) { int s = as[r]; accm[s * 258 + tid] += (double)ps[r][tid]; }
  for (int r = 0; r < 32; ++r) part[((size_t)r * 256 + g) * FF + tid] = accm[r * 258 + tid];
  if (tid < 32) {
    int c = 0;
    for (int r = 0; r < 32; ++r) c += (as[r] == tid) ? 1 : 0;
    cntp[tid * 256 + g] = c;
  }
}

// ---------- kmeans centroid update (fp64, 4-way ILP) ----------
__global__ __launch_bounds__(256) void kmeans_update(const double* __restrict__ part,
                                                     const int* __restrict__ cntp,
                                                     double* __restrict__ cent,
                                                     double* __restrict__ c2) {
  __shared__ double red[256];
  int k = blockIdx.x, f = threadIdx.x;
  double s0 = 0., s1 = 0., s2 = 0., s3 = 0.;
  for (int g = 0; g < 256; g += 4) {
    s0 += part[((size_t)k * 256 + g + 0) * FF + f];
    s1 += part[((size_t)k * 256 + g + 1) * FF + f];
    s2 += part[((size_t)k * 256 + g + 2) * FF + f];
    s3 += part[((size_t)k * 256 + g + 3) * FF + f];
  }
  double acc = (s0 + s1) + (s2 + s3);
  int cnt = 0;
  for (int g = 0; g < 256; ++g) cnt += cntp[k * 256 + g];
  double v = (cnt > 0) ? (acc / (double)cnt) : cent[k * FF + f];
  cent[k * FF + f] = v;
  red[f] = v * v;
  __syncthreads();
  for (int s = 128; s; s >>= 1) { if (f < s) red[f] += red[f + s]; __syncthreads(); }
  if (f == 0) c2[k] = red[0];
}

// ---------- same-concept filtered neighbor lists (from adjbits) ----------
__global__ __launch_bounds__(64) void build_bits(const unsigned long long* __restrict__ adjbits,
                                                 const int* __restrict__ concepts,
                                                 unsigned short* __restrict__ flistT,
                                                 int* __restrict__ fdegv) {
  int i = blockIdx.x, b = blockIdx.y, lane = threadIdx.x;
  int ci = concepts[b * NN + i];
  unsigned long long lmask = (1ULL << lane) - 1ULL;
  int base = 0;
#pragma unroll
  for (int q = 0; q < 8; ++q) {
    unsigned long long wbits = adjbits[((size_t)(b * NN + i)) * 8 + q];
    bool pred = ((wbits >> lane) & 1ULL) && (concepts[b * NN + q * 64 + lane] == ci);
    unsigned long long m = __ballot(pred ? 1 : 0);
    if (pred) {
      int pos = base + __popcll(m & lmask);
      if (pos < FMAXD) flistT[((size_t)b * FMAXD + pos) * NN + i] = (unsigned short)(q * 64 + lane);
    }
    base += __popcll(m);
  }
  if (lane == 0) fdegv[b * NN + i] = base;
}

// ---------- connected components: list-scan + early exit (exact fixed point) ----------
__global__ __launch_bounds__(512) void components_kernel(const unsigned short* __restrict__ flistT,
                                                         const int* __restrict__ fdegv,
                                                         int* __restrict__ comp,
                                                         float* __restrict__ maskF) {
  __shared__ unsigned short LT[FMAXD][512];
  __shared__ int lab[512];
  __shared__ int ids[512];
  int b = blockIdx.x, t = threadIdx.x;
  for (int n = 0; n < FMAXD; ++n) LT[n][t] = flistT[((size_t)b * FMAXD + n) * NN + t];
  int fd = fdegv[b * NN + t];
  if (fd > FMAXD) fd = FMAXD;
  lab[t] = t;
  __syncthreads();
  for (int it = 0; it < CCITERS; ++it) {
    int old = lab[t];
    int m = old;
    for (int n = 0; n < fd; ++n) m = min(m, lab[LT[n][t]]);
    __syncthreads();
    lab[t] = m;
    __syncthreads();
    int a = lab[m];
    __syncthreads();
    lab[t] = a;
    __syncthreads();
    int a2 = lab[a];
    __syncthreads();
    lab[t] = a2;
    int changed = (a2 != old) ? 1 : 0;
    if (__syncthreads_or(changed) == 0) break;  // fixed point reached: rest are identity
  }
  if (t == 0) {
    int run = 0;
    for (int i = 0; i < 512; ++i) { run += (lab[i] == i) ? 1 : 0; ids[i] = run; }
  }
  __syncthreads();
  comp[b * NN + t] = ids[lab[t]];
  maskF[b * NN + t] = (t < ids[511]) ? 1.0f : 0.0f;
}

// ---------- segment sum x_new ----------
__global__ __launch_bounds__(256) void xnew_kernel(const float* __restrict__ H,
                                                   const int* __restrict__ comp,
                                                   float* __restrict__ xnew) {
  int i = blockIdx.x, b = blockIdx.y, f = threadIdx.x;
  int s = comp[b * NN + i] - 1;
  atomicAdd(&xnew[((size_t)(b * NN + s)) * FF + f], H[((size_t)(b * NN + i)) * FF + f]);
}

// ---------- adj_new from adjbits (adj in {0,1}) ----------
__global__ __launch_bounds__(64) void adjnew_kernel(const unsigned long long* __restrict__ adjbits,
                                                    const int* __restrict__ comp,
                                                    float* __restrict__ out) {
  int b = blockIdx.y, lane = threadIdx.x;
  int i = blockIdx.x * 8 + (lane >> 3);
  int q = lane & 7;
  unsigned long long bits = adjbits[((size_t)(b * NN + i)) * 8 + q];
  if (!bits) return;
  int si = comp[b * NN + i] - 1;
  float* ob = out + (size_t)b * NN * NN;
  while (bits) {
    int j = (q << 6) + __builtin_ctzll(bits);
    bits &= bits - 1;
    int sj = comp[b * NN + j] - 1;
    ob[(size_t)si * NN + sj] = 1.0f;  // all writers write 1.0 -> benign race
  }
}

extern "C" void kernel_launch(void* const* d_in, const int* in_sizes, int n_in,
                              void* d_out, int out_size, void* d_ws, size_t ws_size,
                              hipStream_t stream) {
  (void)in_sizes; (void)n_in; (void)out_size; (void)ws_size;
  const float* x   = (const float*)d_in[0];
  const float* adj = (const float*)d_in[1];
  const float* W1 = (const float*)d_in[3];
  const float* b1 = (const float*)d_in[4];
  const float* W2 = (const float*)d_in[5];
  const float* b2 = (const float*)d_in[6];

  float* out = (float*)d_out;
  float* xnew      = out;                       // 2097152 f
  float* adjnew    = out + 2097152;             // 4194304 f
  float* conceptsF = out + 6291456;             // 8192 f
  float* hout      = out + 6299648;             // 2097152 f
  float* maskF     = out + 8396800;             // 8192 f

  char* ws = (char*)d_ws;
  double* dinv = (double*)(ws + 0);                    // 64 KB
  float*  y    = (float*)(ws + 65536);                 // 8 MB
  float*  h1   = (float*)(ws + 8454144);               // 8 MB (reused late for flistT/fdegv)
  double* cent = (double*)(ws + 16842752);             // 64 KB
  double* c2   = (double*)(ws + 16908288);             // 256 B
  double* p2   = (double*)(ws + 16908544);             // 64 KB
  unsigned long long* adjbits = (unsigned long long*)(ws + 16974080);  // 512 KB
  int* assignI = (int*)(ws + 17498368);                // 32 KB (aliased as degv early)
  int* cntp    = (int*)(ws + 17531136);                // 32 KB
  int* comp    = (int*)(ws + 17563904);                // 32 KB
  int* degv    = assignI;  // degv dead before assignI's first write
  double* part = (double*)adjnew;                      // 16 MB in adjnew output region
  unsigned short* nbr = (unsigned short*)xnew;         // 1.5 MB in xnew region (pre-memset)
  unsigned short* flistT = (unsigned short*)h1;        // 1 MB in h1 region (h1 dead post-gemm2)
  int* fdegv = (int*)(ws + 8454144 + 2097152);         // 32 KB in h1 region

  // one pass over adj: bits + neighbor lists + normalization
  build_adjbits<<<dim3(NN, BB), 64, 0, stream>>>(adj, adjbits, dinv, nbr, degv);

  // GCN layer 1 and 2
  gemm_scale<<<dim3(8, 4, BB), 256, 0, stream>>>(x, W1, dinv, y);
  spmv_relu<<<dim3(NN, BB), 256, 0, stream>>>(y, nbr, degv, adjbits, dinv, b1, h1);
  gemm_scale<<<dim3(8, 4, BB), 256, 0, stream>>>(h1, W2, dinv, y);
  spmv_relu<<<dim3(NN, BB), 256, 0, stream>>>(y, nbr, degv, adjbits, dinv, b2, hout);

  // nbr (in xnew region) now dead -> zero x_new
  hipMemsetAsync(xnew, 0, (size_t)2097152 * sizeof(float), stream);

  // kmeans on pts = hout
  const float* pts = hout;
  p2cent_kernel<<<BB * NN, 256, 0, stream>>>(pts, p2, cent, c2);
  for (int it = 0; it < KITERS; ++it) {
    kmeans_assign<<<256, 256, 0, stream>>>(pts, cent, c2, p2, assignI, part, cntp, nullptr);
    kmeans_update<<<NC, 256, 0, stream>>>(part, cntp, cent, c2);
  }
  kmeans_assign<<<256, 256, 0, stream>>>(pts, cent, c2, p2, assignI, part, cntp, conceptsF);

  // part scratch done -> zero adj_new
  hipMemsetAsync(adjnew, 0, (size_t)4194304 * sizeof(float), stream);

  // connected components on same-concept neighbor lists
  build_bits<<<dim3(NN, BB), 64, 0, stream>>>(adjbits, assignI, flistT, fdegv);
  components_kernel<<<BB, 512, 0, stream>>>(flistT, fdegv, comp, maskF);

  // segment reductions
  xnew_kernel<<<dim3(NN, BB), 256, 0, stream>>>(hout, comp, xnew);
  adjnew_kernel<<<dim3(64, BB), 64, 0, stream>>>(adjbits, comp, adjnew);
}

// Round 6
// 629.235 us; speedup vs baseline: 1.6923x; 1.1052x over previous
//
#include <hip/hip_runtime.h>
#include <cstdint>
#include <cstddef>

#define BB 16
#define NN 512
#define FF 256
#define NC 32
#define KITERS 10
#define CCITERS 20
#define MAXD 96    // cap for full-adjacency neighbor list (mean deg ~20)
#define FMAXD 64   // cap for same-concept filtered list

typedef __attribute__((ext_vector_type(4))) double double4_t;

// ---------- adjacency bits + neighbor list + degree normalization ----------
__global__ __launch_bounds__(64) void build_adjbits(const float* __restrict__ adj,
                                                    unsigned long long* __restrict__ adjbits,
                                                    double* __restrict__ dinv,
                                                    unsigned short* __restrict__ nbr,
                                                    int* __restrict__ degv) {
  int i = blockIdx.x, b = blockIdx.y, lane = threadIdx.x;
  const float* row = adj + ((size_t)(b * NN + i)) * NN;
  unsigned long long lmask = (1ULL << lane) - 1ULL;
  int base = 0;
#pragma unroll
  for (int q = 0; q < 8; ++q) {
    bool pred = (row[q * 64 + lane] != 0.0f);
    unsigned long long m = __ballot(pred ? 1 : 0);
    if (lane == 0) adjbits[((size_t)(b * NN + i)) * 8 + q] = m;
    if (pred) {
      int pos = base + __popcll(m & lmask);
      if (pos < MAXD) nbr[((size_t)(b * NN + i)) * MAXD + pos] = (unsigned short)(q * 64 + lane);
    }
    base += __popcll(m);
  }
  if (lane == 0) {
    degv[b * NN + i] = base;
    double tot = (double)base + 1.0;  // a = adj + I; clip no-op since >=1
    dinv[b * NN + i] = 1.0 / sqrt(tot);
  }
}

// ---------- GEMM: Y[b] = dinv_row * (X[b] @ W), fp64 accumulate ----------
__global__ __launch_bounds__(256) void gemm_scale(const float* __restrict__ X,
                                                  const float* __restrict__ W,
                                                  const double* __restrict__ dinv,
                                                  float* __restrict__ Y) {
  __shared__ float As[16][68];
  __shared__ float Bs[16][64];
  int bm = blockIdx.x, bn = blockIdx.y, b = blockIdx.z;
  int tid = threadIdx.x;
  int tx = tid & 15, ty = tid >> 4;
  const float* Xb = X + (size_t)b * NN * FF;
  float* Yb = Y + (size_t)b * NN * FF;
  double acc[4][4] = {};
  for (int kt = 0; kt < FF; kt += 16) {
    {
      int m = tid >> 2, kq = (tid & 3) * 4;
      const float4 v = *(const float4*)&Xb[(size_t)(bm * 64 + m) * FF + kt + kq];
      As[kq + 0][m] = v.x; As[kq + 1][m] = v.y; As[kq + 2][m] = v.z; As[kq + 3][m] = v.w;
    }
    {
      int k = tid >> 4, n4 = (tid & 15) * 4;
      *(float4*)&Bs[k][n4] = *(const float4*)&W[(size_t)(kt + k) * FF + bn * 64 + n4];
    }
    __syncthreads();
#pragma unroll
    for (int k = 0; k < 16; ++k) {
      float4 a = *(const float4*)&As[k][ty * 4];
      float4 bv = *(const float4*)&Bs[k][tx * 4];
      double ax = a.x, ay = a.y, az = a.z, aw = a.w;
      double bx = bv.x, by = bv.y, bz = bv.z, bw = bv.w;
      acc[0][0] += ax * bx; acc[0][1] += ax * by; acc[0][2] += ax * bz; acc[0][3] += ax * bw;
      acc[1][0] += ay * bx; acc[1][1] += ay * by; acc[1][2] += ay * bz; acc[1][3] += ay * bw;
      acc[2][0] += az * bx; acc[2][1] += az * by; acc[2][2] += az * bz; acc[2][3] += az * bw;
      acc[3][0] += aw * bx; acc[3][1] += aw * by; acc[3][2] += aw * bz; acc[3][3] += aw * bw;
    }
    __syncthreads();
  }
#pragma unroll
  for (int i = 0; i < 4; ++i) {
    int row = bm * 64 + ty * 4 + i;
    double di = dinv[b * NN + row];
    float4 v;
    v.x = (float)(di * acc[i][0]); v.y = (float)(di * acc[i][1]);
    v.z = (float)(di * acc[i][2]); v.w = (float)(di * acc[i][3]);
    *(float4*)&Yb[(size_t)row * FF + bn * 64 + tx * 4] = v;
  }
}

// ---------- SpMV via neighbor list: H = relu(dinv_i*((adj+I)@y)_i + bias) ----------
__global__ __launch_bounds__(256) void spmv_relu(const float* __restrict__ Y,
                                                 const unsigned short* __restrict__ nbr,
                                                 const int* __restrict__ degv,
                                                 const unsigned long long* __restrict__ adjbits,
                                                 const double* __restrict__ dinv,
                                                 const float* __restrict__ bias,
                                                 float* __restrict__ H) {
  int i = blockIdx.x, b = blockIdx.y, f = threadIdx.x;
  int row = b * NN + i;
  const float* Yb = Y + (size_t)b * NN * FF;
  double z = (double)Yb[(size_t)i * FF + f];  // +I term
  int deg = degv[row];
  if (deg <= MAXD) {
    const unsigned short* lst = nbr + (size_t)row * MAXD;
    int n = 0;
    for (; n + 4 <= deg; n += 4) {
      int j0 = lst[n], j1 = lst[n + 1], j2 = lst[n + 2], j3 = lst[n + 3];
      float v0 = Yb[(size_t)j0 * FF + f];
      float v1 = Yb[(size_t)j1 * FF + f];
      float v2 = Yb[(size_t)j2 * FF + f];
      float v3 = Yb[(size_t)j3 * FF + f];
      z += (double)v0; z += (double)v1; z += (double)v2; z += (double)v3;
    }
    for (; n < deg; ++n) z += (double)Yb[(size_t)lst[n] * FF + f];
  } else {
    const unsigned long long* brow = adjbits + (size_t)row * 8;
    for (int q = 0; q < 8; ++q) {
      unsigned long long bits = brow[q];
      while (bits) {
        int j = (q << 6) + __builtin_ctzll(bits);
        bits &= bits - 1;
        z += (double)Yb[(size_t)j * FF + f];
      }
    }
  }
  double h = dinv[row] * z + (double)bias[f];
  H[((size_t)row) * FF + f] = (h > 0.0) ? (float)h : 0.0f;
}

// ---------- p2 for all points + centroid init (first 32 rows) ----------
__global__ __launch_bounds__(256) void p2cent_kernel(const float* __restrict__ pts,
                                                     double* __restrict__ p2,
                                                     double* __restrict__ cent) {
  __shared__ double red[256];
  int p = blockIdx.x, t = threadIdx.x;
  double v = (double)pts[(size_t)p * FF + t];
  if (p < NC) cent[p * FF + t] = v;
  red[t] = v * v;
  __syncthreads();
  for (int s = 128; s; s >>= 1) { if (t < s) red[t] += red[t + s]; __syncthreads(); }
  if (t == 0) p2[p] = red[0];
}

// ---------- kmeans assign: fp64 MFMA d2 with layout self-identification ----------
// c2 (centroid squared norms) computed in-block from csT in fixed k-ascending order.
__global__ __launch_bounds__(256) void kmeans_assign(const float* __restrict__ pts,
                                                     const double* __restrict__ cent,
                                                     const double* __restrict__ p2,
                                                     int* __restrict__ assignI,
                                                     double* __restrict__ part,
                                                     int* __restrict__ cntp,
                                                     float* __restrict__ conceptsF) {
  __shared__ float ps[32][260];      // point rows (fp32)
  __shared__ double csT[256][35];    // csT[k][c] (fp64), reused as acc[32][258]
  __shared__ double d2s[32][33];
  __shared__ double c2s[32];
  __shared__ double want[3];         // scalar ref dots: (p0,c0),(p0,c1),(p1,c0)
  __shared__ double probe_raw[2][2]; // wave0 lanes 0/1: acc[0],acc[1]
  __shared__ int as[32];
  __shared__ int hyp;                // 0=H1, 1=H2(transposed), 2=scalar fallback
  int g = blockIdx.x, tid = threadIdx.x;

  for (int r = 0; r < 32; ++r) ps[r][tid] = pts[(size_t)(g * 32 + r) * FF + tid];
  for (int rep = 0; rep < 32; ++rep) csT[tid][rep] = cent[rep * FF + tid];
  __syncthreads();

  // c2s[c] = sum_k cent[c][k]^2, fixed k-ascending order (deterministic)
  if (tid < 32) {
    double s = 0.;
    for (int k = 0; k < FF; ++k) { double cv = csT[k][tid]; s += cv * cv; }
    c2s[tid] = s;
  }

  // 4 waves, each a 16x16 fp64 tile of dots = pts_tile . cent_tileT
  int lane = tid & 63, w = tid >> 6;
  int prow = (w >> 1) * 16, ccol = (w & 1) * 16;
  int r16 = lane & 15, kg = lane >> 4;
  double4_t acc = {0.0, 0.0, 0.0, 0.0};
  for (int kt = 0; kt < FF; kt += 4) {
    double a = (double)ps[prow + r16][kt + kg];
    double bv = csT[kt + kg][ccol + r16];
    acc = __builtin_amdgcn_mfma_f64_16x16x4f64(a, bv, acc, 0, 0, 0);
  }
  if (tid < 2) { probe_raw[tid][0] = acc[0]; probe_raw[tid][1] = acc[1]; }
  __syncthreads();

  // asymmetric reference probes (3 waves, one dot each)
  if (tid < 192) {
    int pw = tid >> 6;                  // 0:(0,0) 1:(0,1) 2:(1,0)
    int pr = (pw == 2) ? 1 : 0;
    int pc = (pw == 1) ? 1 : 0;
    double partial = 0.0;
#pragma unroll
    for (int kk = 0; kk < 4; ++kk)
      partial += (double)ps[pr][lane * 4 + kk] * csT[lane * 4 + kk][pc];
    for (int off = 32; off; off >>= 1) partial += __shfl_xor(partial, off, 64);
    if (lane == 0) want[pw] = partial;
  }
  __syncthreads();
  if (tid == 0) {
    double w00 = want[0], w01 = want[1], w10 = want[2];
    double m00 = probe_raw[0][0], mA = probe_raw[1][0], mB = probe_raw[0][1];
    auto near = [](double a, double b) { return fabs(a - b) <= 1e-9 * (1.0 + fabs(b)); };
    bool ok00 = near(m00, w00);
    bool h1 = ok00 && near(mA, w01) && near(mB, w10);
    bool h2 = ok00 && near(mB, w01) && near(mA, w10);
    hyp = h1 ? 0 : (h2 ? 1 : 2);
  }
  __syncthreads();
  int hh = hyp;
  if (hh == 0) {
#pragma unroll
    for (int ii = 0; ii < 4; ++ii) {
      int row = prow + kg * 4 + ii, col = ccol + r16;
      d2s[row][col] = (p2[g * 32 + row] - 2.0 * acc[ii]) + c2s[col];
    }
  } else if (hh == 1) {
#pragma unroll
    for (int ii = 0; ii < 4; ++ii) {
      int row = prow + r16, col = ccol + kg * 4 + ii;
      d2s[row][col] = (p2[g * 32 + row] - 2.0 * acc[ii]) + c2s[col];
    }
  }
  __syncthreads();
  if (hh == 2) {  // proven scalar fallback (block-uniform)
    int p0 = tid >> 4, c0 = tid & 15;
    double a00 = 0., a01 = 0., a10 = 0., a11 = 0.;
    for (int k = 0; k < FF; ++k) {
      double pa = (double)ps[p0][k], pb = (double)ps[p0 + 16][k];
      double ca = csT[k][c0], cb = csT[k][c0 + 16];
      a00 += pa * ca; a01 += pa * cb; a10 += pb * ca; a11 += pb * cb;
    }
    double pp0 = p2[g * 32 + p0], pp1 = p2[g * 32 + p0 + 16];
    double cc0 = c2s[c0], cc1 = c2s[c0 + 16];
    d2s[p0][c0]           = (pp0 - 2.0 * a00) + cc0;
    d2s[p0][c0 + 16]      = (pp0 - 2.0 * a01) + cc1;
    d2s[p0 + 16][c0]      = (pp1 - 2.0 * a10) + cc0;
    d2s[p0 + 16][c0 + 16] = (pp1 - 2.0 * a11) + cc1;
  }
  __syncthreads();

  if (tid < 32) {
    double m = d2s[tid][0];
    int idx = 0;
    for (int c = 1; c < 32; ++c) {
      double v = d2s[tid][c];
      if (v < m) { m = v; idx = c; }  // strict <: first-wins like argmin
    }
    as[tid] = idx;
    assignI[g * 32 + tid] = idx;
    if (conceptsF) conceptsF[g * 32 + tid] = (float)idx;
  }
  // reuse csT storage as fp64 accumulators acc[32][258] (all csT reads done)
  double* accm = &csT[0][0];
  for (int r = 0; r < 32; ++r) accm[r * 258 + tid] = 0.0;
  __syncthreads();
  for (int r = 0; r < 32; ++r) { int s = as[r]; accm[s * 258 + tid] += (double)ps[r][tid]; }
  for (int r = 0; r < 32; ++r) part[((size_t)r * 256 + g) * FF + tid] = accm[r * 258 + tid];
  if (tid < 32) {
    int c = 0;
    for (int r = 0; r < 32; ++r) c += (as[r] == tid) ? 1 : 0;
    cntp[tid * 256 + g] = c;
  }
}

// ---------- kmeans centroid update: grid (NC, 8), deterministic fixed-order tree ----------
__global__ __launch_bounds__(256) void kmeans_update(const double* __restrict__ part,
                                                     const int* __restrict__ cntp,
                                                     double* __restrict__ cent) {
  __shared__ double red[8][33];
  __shared__ int cred[256];
  int k = blockIdx.x, fc = blockIdx.y;
  int tid = threadIdx.x;
  int fl = tid & 31, gl = tid >> 5;   // gl = 0..7
  int f = fc * 32 + fl;
  double s = 0.;
  for (int gg = 0; gg < 32; ++gg) {
    int g = gl + gg * 8;              // fixed mapping -> deterministic order
    s += part[((size_t)k * 256 + g) * FF + f];
  }
  red[gl][fl] = s;
  cred[tid] = cntp[k * 256 + tid];
  __syncthreads();
  for (int q = 128; q; q >>= 1) { if (tid < q) cred[tid] += cred[tid + q]; __syncthreads(); }
  if (gl == 0) {
    double acc = 0.;
    for (int q = 0; q < 8; ++q) acc += red[q][fl];  // fixed ascending order
    int cnt = cred[0];
    double v = (cnt > 0) ? (acc / (double)cnt) : cent[k * FF + f];
    cent[k * FF + f] = v;
  }
}

// ---------- same-concept filtered neighbor lists (from adjbits) ----------
__global__ __launch_bounds__(64) void build_bits(const unsigned long long* __restrict__ adjbits,
                                                 const int* __restrict__ concepts,
                                                 unsigned short* __restrict__ flistT,
                                                 int* __restrict__ fdegv) {
  int i = blockIdx.x, b = blockIdx.y, lane = threadIdx.x;
  int ci = concepts[b * NN + i];
  unsigned long long lmask = (1ULL << lane) - 1ULL;
  int base = 0;
#pragma unroll
  for (int q = 0; q < 8; ++q) {
    unsigned long long wbits = adjbits[((size_t)(b * NN + i)) * 8 + q];
    bool pred = ((wbits >> lane) & 1ULL) && (concepts[b * NN + q * 64 + lane] == ci);
    unsigned long long m = __ballot(pred ? 1 : 0);
    if (pred) {
      int pos = base + __popcll(m & lmask);
      if (pos < FMAXD) flistT[((size_t)b * FMAXD + pos) * NN + i] = (unsigned short)(q * 64 + lane);
    }
    base += __popcll(m);
  }
  if (lane == 0) fdegv[b * NN + i] = base;
}

// ---------- connected components: list-scan + early exit (exact fixed point) ----------
__global__ __launch_bounds__(512) void components_kernel(const unsigned short* __restrict__ flistT,
                                                         const int* __restrict__ fdegv,
                                                         int* __restrict__ comp,
                                                         float* __restrict__ maskF) {
  __shared__ unsigned short LT[FMAXD][512];
  __shared__ int lab[512];
  __shared__ int ids[512];
  int b = blockIdx.x, t = threadIdx.x;
  for (int n = 0; n < FMAXD; ++n) LT[n][t] = flistT[((size_t)b * FMAXD + n) * NN + t];
  int fd = fdegv[b * NN + t];
  if (fd > FMAXD) fd = FMAXD;
  lab[t] = t;
  __syncthreads();
  for (int it = 0; it < CCITERS; ++it) {
    int old = lab[t];
    int m = old;
    for (int n = 0; n < fd; ++n) m = min(m, lab[LT[n][t]]);
    __syncthreads();
    lab[t] = m;
    __syncthreads();
    int a = lab[m];
    __syncthreads();
    lab[t] = a;
    __syncthreads();
    int a2 = lab[a];
    __syncthreads();
    lab[t] = a2;
    int changed = (a2 != old) ? 1 : 0;
    if (__syncthreads_or(changed) == 0) break;  // fixed point: rest are identity
  }
  if (t == 0) {
    int run = 0;
    for (int i = 0; i < 512; ++i) { run += (lab[i] == i) ? 1 : 0; ids[i] = run; }
  }
  __syncthreads();
  comp[b * NN + t] = ids[lab[t]];
  maskF[b * NN + t] = (t < ids[511]) ? 1.0f : 0.0f;
}

// ---------- segment sum x_new ----------
__global__ __launch_bounds__(256) void xnew_kernel(const float* __restrict__ H,
                                                   const int* __restrict__ comp,
                                                   float* __restrict__ xnew) {
  int i = blockIdx.x, b = blockIdx.y, f = threadIdx.x;
  int s = comp[b * NN + i] - 1;
  atomicAdd(&xnew[((size_t)(b * NN + s)) * FF + f], H[((size_t)(b * NN + i)) * FF + f]);
}

// ---------- adj_new from adjbits (adj in {0,1}) ----------
__global__ __launch_bounds__(64) void adjnew_kernel(const unsigned long long* __restrict__ adjbits,
                                                    const int* __restrict__ comp,
                                                    float* __restrict__ out) {
  int b = blockIdx.y, lane = threadIdx.x;
  int i = blockIdx.x * 8 + (lane >> 3);
  int q = lane & 7;
  unsigned long long bits = adjbits[((size_t)(b * NN + i)) * 8 + q];
  if (!bits) return;
  int si = comp[b * NN + i] - 1;
  float* ob = out + (size_t)b * NN * NN;
  while (bits) {
    int j = (q << 6) + __builtin_ctzll(bits);
    bits &= bits - 1;
    int sj = comp[b * NN + j] - 1;
    ob[(size_t)si * NN + sj] = 1.0f;  // all writers write 1.0 -> benign race
  }
}

extern "C" void kernel_launch(void* const* d_in, const int* in_sizes, int n_in,
                              void* d_out, int out_size, void* d_ws, size_t ws_size,
                              hipStream_t stream) {
  (void)in_sizes; (void)n_in; (void)out_size; (void)ws_size;
  const float* x   = (const float*)d_in[0];
  const float* adj = (const float*)d_in[1];
  const float* W1 = (const float*)d_in[3];
  const float* b1 = (const float*)d_in[4];
  const float* W2 = (const float*)d_in[5];
  const float* b2 = (const float*)d_in[6];

  float* out = (float*)d_out;
  float* xnew      = out;                       // 2097152 f
  float* adjnew    = out + 2097152;             // 4194304 f
  float* conceptsF = out + 6291456;             // 8192 f
  float* hout      = out + 6299648;             // 2097152 f
  float* maskF     = out + 8396800;             // 8192 f

  char* ws = (char*)d_ws;
  double* dinv = (double*)(ws + 0);                    // 64 KB
  float*  y    = (float*)(ws + 65536);                 // 8 MB
  float*  h1   = (float*)(ws + 8454144);               // 8 MB (reused late for flistT/fdegv)
  double* cent = (double*)(ws + 16842752);             // 64 KB
  double* p2   = (double*)(ws + 16908544);             // 64 KB
  unsigned long long* adjbits = (unsigned long long*)(ws + 16974080);  // 512 KB
  int* assignI = (int*)(ws + 17498368);                // 32 KB (aliased as degv early)
  int* cntp    = (int*)(ws + 17531136);                // 32 KB
  int* comp    = (int*)(ws + 17563904);                // 32 KB
  int* degv    = assignI;  // degv dead before assignI's first write
  double* part = (double*)adjnew;                      // 16 MB in adjnew output region
  unsigned short* nbr = (unsigned short*)xnew;         // 1.5 MB in xnew region (pre-memset)
  unsigned short* flistT = (unsigned short*)h1;        // 1 MB in h1 region (h1 dead post-gemm2)
  int* fdegv = (int*)(ws + 8454144 + 2097152);         // 32 KB in h1 region

  // one pass over adj: bits + neighbor lists + normalization
  build_adjbits<<<dim3(NN, BB), 64, 0, stream>>>(adj, adjbits, dinv, nbr, degv);

  // GCN layer 1 and 2
  gemm_scale<<<dim3(8, 4, BB), 256, 0, stream>>>(x, W1, dinv, y);
  spmv_relu<<<dim3(NN, BB), 256, 0, stream>>>(y, nbr, degv, adjbits, dinv, b1, h1);
  gemm_scale<<<dim3(8, 4, BB), 256, 0, stream>>>(h1, W2, dinv, y);
  spmv_relu<<<dim3(NN, BB), 256, 0, stream>>>(y, nbr, degv, adjbits, dinv, b2, hout);

  // nbr (in xnew region) now dead -> zero x_new
  hipMemsetAsync(xnew, 0, (size_t)2097152 * sizeof(float), stream);

  // kmeans on pts = hout
  const float* pts = hout;
  p2cent_kernel<<<BB * NN, 256, 0, stream>>>(pts, p2, cent);
  for (int it = 0; it < KITERS; ++it) {
    kmeans_assign<<<256, 256, 0, stream>>>(pts, cent, p2, assignI, part, cntp, nullptr);
    kmeans_update<<<dim3(NC, 8), 256, 0, stream>>>(part, cntp, cent);
  }
  kmeans_assign<<<256, 256, 0, stream>>>(pts, cent, p2, assignI, part, cntp, conceptsF);

  // part scratch done -> zero adj_new
  hipMemsetAsync(adjnew, 0, (size_t)4194304 * sizeof(float), stream);

  // connected components on same-concept neighbor lists
  build_bits<<<dim3(NN, BB), 64, 0, stream>>>(adjbits, assignI, flistT, fdegv);
  components_kernel<<<BB, 512, 0, stream>>>(flistT, fdegv, comp, maskF);

  // segment reductions
  xnew_kernel<<<dim3(NN, BB), 256, 0, stream>>>(hout, comp, xnew);
  adjnew_kernel<<<dim3(64, BB), 64, 0, stream>>>(adjbits, comp, adjnew);
}

// Round 8
// 614.424 us; speedup vs baseline: 1.7331x; 1.0241x over previous
//
#include <hip/hip_runtime.h>
#include <cstdint>
#include <cstddef>

#define BB 16
#define NN 512
#define FF 256
#define NC 32
#define KITERS 10
#define CCITERS 20
#define MAXD 96    // cap for full-adjacency neighbor list (mean deg ~20)
#define FMAXD 64   // cap for same-concept filtered list

typedef __attribute__((ext_vector_type(4))) double double4_t;

// ---------- adjacency bits + neighbor list + degree normalization ----------
__global__ __launch_bounds__(64) void build_adjbits(const float* __restrict__ adj,
                                                    unsigned long long* __restrict__ adjbits,
                                                    double* __restrict__ dinv,
                                                    unsigned short* __restrict__ nbr,
                                                    int* __restrict__ degv) {
  int i = blockIdx.x, b = blockIdx.y, lane = threadIdx.x;
  const float* row = adj + ((size_t)(b * NN + i)) * NN;
  unsigned long long lmask = (1ULL << lane) - 1ULL;
  int base = 0;
#pragma unroll
  for (int q = 0; q < 8; ++q) {
    bool pred = (row[q * 64 + lane] != 0.0f);
    unsigned long long m = __ballot(pred ? 1 : 0);
    if (lane == 0) adjbits[((size_t)(b * NN + i)) * 8 + q] = m;
    if (pred) {
      int pos = base + __popcll(m & lmask);
      if (pos < MAXD) nbr[((size_t)(b * NN + i)) * MAXD + pos] = (unsigned short)(q * 64 + lane);
    }
    base += __popcll(m);
  }
  if (lane == 0) {
    degv[b * NN + i] = base;
    double tot = (double)base + 1.0;  // a = adj + I; clip no-op since >=1
    dinv[b * NN + i] = 1.0 / sqrt(tot);
  }
}

// ---------- GEMM: Y[b] = dinv_row * (X[b] @ W), fp64 accumulate ----------
__global__ __launch_bounds__(256) void gemm_scale(const float* __restrict__ X,
                                                  const float* __restrict__ W,
                                                  const double* __restrict__ dinv,
                                                  float* __restrict__ Y) {
  __shared__ float As[16][68];
  __shared__ float Bs[16][64];
  int bm = blockIdx.x, bn = blockIdx.y, b = blockIdx.z;
  int tid = threadIdx.x;
  int tx = tid & 15, ty = tid >> 4;
  const float* Xb = X + (size_t)b * NN * FF;
  float* Yb = Y + (size_t)b * NN * FF;
  double acc[4][4] = {};
  for (int kt = 0; kt < FF; kt += 16) {
    {
      int m = tid >> 2, kq = (tid & 3) * 4;
      const float4 v = *(const float4*)&Xb[(size_t)(bm * 64 + m) * FF + kt + kq];
      As[kq + 0][m] = v.x; As[kq + 1][m] = v.y; As[kq + 2][m] = v.z; As[kq + 3][m] = v.w;
    }
    {
      int k = tid >> 4, n4 = (tid & 15) * 4;
      *(float4*)&Bs[k][n4] = *(const float4*)&W[(size_t)(kt + k) * FF + bn * 64 + n4];
    }
    __syncthreads();
#pragma unroll
    for (int k = 0; k < 16; ++k) {
      float4 a = *(const float4*)&As[k][ty * 4];
      float4 bv = *(const float4*)&Bs[k][tx * 4];
      double ax = a.x, ay = a.y, az = a.z, aw = a.w;
      double bx = bv.x, by = bv.y, bz = bv.z, bw = bv.w;
      acc[0][0] += ax * bx; acc[0][1] += ax * by; acc[0][2] += ax * bz; acc[0][3] += ax * bw;
      acc[1][0] += ay * bx; acc[1][1] += ay * by; acc[1][2] += ay * bz; acc[1][3] += ay * bw;
      acc[2][0] += az * bx; acc[2][1] += az * by; acc[2][2] += az * bz; acc[2][3] += az * bw;
      acc[3][0] += aw * bx; acc[3][1] += aw * by; acc[3][2] += aw * bz; acc[3][3] += aw * bw;
    }
    __syncthreads();
  }
#pragma unroll
  for (int i = 0; i < 4; ++i) {
    int row = bm * 64 + ty * 4 + i;
    double di = dinv[b * NN + row];
    float4 v;
    v.x = (float)(di * acc[i][0]); v.y = (float)(di * acc[i][1]);
    v.z = (float)(di * acc[i][2]); v.w = (float)(di * acc[i][3]);
    *(float4*)&Yb[(size_t)row * FF + bn * 64 + tx * 4] = v;
  }
}

// ---------- SpMV + optional (p2 / cent0 / kmeans-buffer zeroing) ----------
__global__ __launch_bounds__(256) void spmv_relu(const float* __restrict__ Y,
                                                 const unsigned short* __restrict__ nbr,
                                                 const int* __restrict__ degv,
                                                 const unsigned long long* __restrict__ adjbits,
                                                 const double* __restrict__ dinv,
                                                 const float* __restrict__ bias,
                                                 float* __restrict__ H,
                                                 double* __restrict__ p2out,
                                                 double* __restrict__ cent0,
                                                 char* __restrict__ zbuf) {
  __shared__ double red[256];
  int i = blockIdx.x, b = blockIdx.y, f = threadIdx.x;
  int row = b * NN + i;
  const float* Yb = Y + (size_t)b * NN * FF;
  double z = (double)Yb[(size_t)i * FF + f];  // +I term
  int deg = degv[row];
  if (deg <= MAXD) {
    const unsigned short* lst = nbr + (size_t)row * MAXD;
    int n = 0;
    for (; n + 4 <= deg; n += 4) {
      int j0 = lst[n], j1 = lst[n + 1], j2 = lst[n + 2], j3 = lst[n + 3];
      float v0 = Yb[(size_t)j0 * FF + f];
      float v1 = Yb[(size_t)j1 * FF + f];
      float v2 = Yb[(size_t)j2 * FF + f];
      float v3 = Yb[(size_t)j3 * FF + f];
      z += (double)v0; z += (double)v1; z += (double)v2; z += (double)v3;
    }
    for (; n < deg; ++n) z += (double)Yb[(size_t)lst[n] * FF + f];
  } else {
    const unsigned long long* brow = adjbits + (size_t)row * 8;
    for (int q = 0; q < 8; ++q) {
      unsigned long long bits = brow[q];
      while (bits) {
        int j = (q << 6) + __builtin_ctzll(bits);
        bits &= bits - 1;
        z += (double)Yb[(size_t)j * FF + f];
      }
    }
  }
  double h = dinv[row] * z + (double)bias[f];
  float hf = (h > 0.0) ? (float)h : 0.0f;
  H[((size_t)row) * FF + f] = hf;

  if (p2out) {  // uniform branch (kernel arg)
    double v = (double)hf;
    red[f] = v * v;
    __syncthreads();
    for (int s = 128; s; s >>= 1) { if (f < s) red[f] += red[f + s]; __syncthreads(); }
    if (f == 0) p2out[row] = red[0];
    if (b == 0 && i < NC) cent0[i * FF + f] = (double)hf;
    if (b == 2 && i < 353) {  // zero kmeans buffers (h1 region, dead after gemm2)
      float4 z4 = {0.f, 0.f, 0.f, 0.f};
      ((float4*)(zbuf + (size_t)i * 4096))[f] = z4;
    }
  }
}

// ---------- kmeans iteration: centroid recompute + MFMA d2 + argmin + atomic sums ----------
__global__ __launch_bounds__(256) void kmeans_it(const float* __restrict__ pts,
                                                 const double* __restrict__ cent0,
                                                 double* __restrict__ centprev,
                                                 double* __restrict__ cent_sum,
                                                 int* __restrict__ cntI,
                                                 const double* __restrict__ p2,
                                                 int* __restrict__ assignI,
                                                 float* __restrict__ conceptsF,
                                                 int it) {
  __shared__ float ps[32][260];
  __shared__ double csT[256][35];    // csT[k][c]; reused as acc[32][258]
  __shared__ double d2s[32][33];
  __shared__ double c2s[32];
  __shared__ double want[3];
  __shared__ double probe_raw[2][2];
  __shared__ int as[32];
  __shared__ int lcs[32];
  __shared__ int hyp;
  int g = blockIdx.x, tid = threadIdx.x;

  for (int r = 0; r < 32; ++r) ps[r][tid] = pts[(size_t)(g * 32 + r) * FF + tid];
  // centroids: it==0 -> cent0 ; else cnt>0 ? cent_sum/cnt : centprev  (same div as R6 update)
  if (it == 0) {
    for (int rep = 0; rep < 32; ++rep) csT[tid][rep] = cent0[rep * FF + tid];
  } else {
    for (int rep = 0; rep < 32; ++rep) {
      int ct = cntI[(it - 1) * 32 + rep];
      double v = (ct > 0) ? (cent_sum[((size_t)(it - 1) * 32 + rep) * FF + tid] / (double)ct)
                          : centprev[((size_t)(it - 1) * 32 + rep) * FF + tid];
      csT[tid][rep] = v;
    }
  }
  __syncthreads();
  if (g < 32) centprev[((size_t)it * 32 + g) * FF + tid] = csT[tid][g];  // snapshot for empty-cluster chain

  if (tid < 32) {
    double s = 0.;
    for (int k = 0; k < FF; ++k) { double cv = csT[k][tid]; s += cv * cv; }
    c2s[tid] = s;
  }

  int lane = tid & 63, w = tid >> 6;
  int prow = (w >> 1) * 16, ccol = (w & 1) * 16;
  int r16 = lane & 15, kg = lane >> 4;
  double4_t acc = {0.0, 0.0, 0.0, 0.0};
  for (int kt = 0; kt < FF; kt += 4) {
    double a = (double)ps[prow + r16][kt + kg];
    double bv = csT[kt + kg][ccol + r16];
    acc = __builtin_amdgcn_mfma_f64_16x16x4f64(a, bv, acc, 0, 0, 0);
  }
  if (tid < 2) { probe_raw[tid][0] = acc[0]; probe_raw[tid][1] = acc[1]; }
  __syncthreads();

  if (tid < 192) {  // asymmetric layout probes
    int pw = tid >> 6;                  // 0:(0,0) 1:(0,1) 2:(1,0)
    int pr = (pw == 2) ? 1 : 0;
    int pc = (pw == 1) ? 1 : 0;
    double partial = 0.0;
#pragma unroll
    for (int kk = 0; kk < 4; ++kk)
      partial += (double)ps[pr][lane * 4 + kk] * csT[lane * 4 + kk][pc];
    for (int off = 32; off; off >>= 1) partial += __shfl_xor(partial, off, 64);
    if (lane == 0) want[pw] = partial;
  }
  __syncthreads();
  if (tid == 0) {
    double w00 = want[0], w01 = want[1], w10 = want[2];
    double m00 = probe_raw[0][0], mA = probe_raw[1][0], mB = probe_raw[0][1];
    auto near = [](double a, double b) { return fabs(a - b) <= 1e-9 * (1.0 + fabs(b)); };
    bool ok00 = near(m00, w00);
    bool h1 = ok00 && near(mA, w01) && near(mB, w10);
    bool h2 = ok00 && near(mB, w01) && near(mA, w10);
    hyp = h1 ? 0 : (h2 ? 1 : 2);
  }
  __syncthreads();
  int hh = hyp;
  if (hh == 0) {
#pragma unroll
    for (int ii = 0; ii < 4; ++ii) {
      int row = prow + kg * 4 + ii, col = ccol + r16;
      d2s[row][col] = (p2[g * 32 + row] - 2.0 * acc[ii]) + c2s[col];
    }
  } else if (hh == 1) {
#pragma unroll
    for (int ii = 0; ii < 4; ++ii) {
      int row = prow + r16, col = ccol + kg * 4 + ii;
      d2s[row][col] = (p2[g * 32 + row] - 2.0 * acc[ii]) + c2s[col];
    }
  }
  __syncthreads();
  if (hh == 2) {  // proven scalar fallback (block-uniform)
    int p0 = tid >> 4, c0 = tid & 15;
    double a00 = 0., a01 = 0., a10 = 0., a11 = 0.;
    for (int k = 0; k < FF; ++k) {
      double pa = (double)ps[p0][k], pb = (double)ps[p0 + 16][k];
      double ca = csT[k][c0], cb = csT[k][c0 + 16];
      a00 += pa * ca; a01 += pa * cb; a10 += pb * ca; a11 += pb * cb;
    }
    double pp0 = p2[g * 32 + p0], pp1 = p2[g * 32 + p0 + 16];
    double cc0 = c2s[c0], cc1 = c2s[c0 + 16];
    d2s[p0][c0]           = (pp0 - 2.0 * a00) + cc0;
    d2s[p0][c0 + 16]      = (pp0 - 2.0 * a01) + cc1;
    d2s[p0 + 16][c0]      = (pp1 - 2.0 * a10) + cc0;
    d2s[p0 + 16][c0 + 16] = (pp1 - 2.0 * a11) + cc1;
  }
  __syncthreads();

  if (tid < 32) {
    double m = d2s[tid][0];
    int idx = 0;
    for (int c = 1; c < 32; ++c) {
      double v = d2s[tid][c];
      if (v < m) { m = v; idx = c; }  // strict <: first-wins like argmin
    }
    as[tid] = idx;
    assignI[g * 32 + tid] = idx;
    if (conceptsF) conceptsF[g * 32 + tid] = (float)idx;
  }
  if (it == KITERS) return;  // final assign: no accumulation

  double* accm = &csT[0][0];  // reuse csT storage
  for (int r = 0; r < 32; ++r) accm[r * 258 + tid] = 0.0;
  __syncthreads();
  for (int r = 0; r < 32; ++r) { int s = as[r]; accm[s * 258 + tid] += (double)ps[r][tid]; }
  if (tid < 32) {
    int c = 0;
    for (int r = 0; r < 32; ++r) c += (as[r] == tid) ? 1 : 0;
    lcs[tid] = c;
    if (c > 0) atomicAdd(&cntI[it * 32 + tid], c);
  }
  __syncthreads();
  for (int r = 0; r < 32; ++r) {
    if (lcs[r] > 0)
      unsafeAtomicAdd(&cent_sum[((size_t)it * 32 + r) * FF + tid], accm[r * 258 + tid]);
  }
}

// ---------- connected components: inline concept-filtered lists + early exit + scan ----------
__global__ __launch_bounds__(512) void components_kernel(const unsigned long long* __restrict__ adjbits,
                                                         const int* __restrict__ concepts,
                                                         int* __restrict__ comp,
                                                         float* __restrict__ maskF) {
  __shared__ int cI[512];
  __shared__ unsigned short LT[FMAXD][512];
  __shared__ int lab[512];
  __shared__ int ids[512];
  int b = blockIdx.x, t = threadIdx.x;
  cI[t] = concepts[b * NN + t];
  __syncthreads();
  int ci = cI[t];
  const unsigned long long* brow = adjbits + ((size_t)(b * NN + t)) * 8;
  int fd = 0;
#pragma unroll
  for (int q = 0; q < 8; ++q) {
    unsigned long long bits = brow[q];
    while (bits) {
      int j = (q << 6) + __builtin_ctzll(bits);
      bits &= bits - 1;
      if (cI[j] == ci) { if (fd < FMAXD) LT[fd][t] = (unsigned short)j; ++fd; }
    }
  }
  if (fd > FMAXD) fd = FMAXD;
  lab[t] = t;
  __syncthreads();
  for (int it = 0; it < CCITERS; ++it) {
    int old = lab[t];
    int m = old;
    for (int n = 0; n < fd; ++n) m = min(m, lab[LT[n][t]]);
    __syncthreads();
    lab[t] = m;
    __syncthreads();
    int a = lab[m];
    __syncthreads();
    lab[t] = a;
    __syncthreads();
    int a2 = lab[a];
    __syncthreads();
    lab[t] = a2;
    int changed = (a2 != old) ? 1 : 0;
    if (__syncthreads_or(changed) == 0) break;  // fixed point: rest are identity
  }
  // inclusive scan of is_root (Hillis-Steele, exact integer)
  ids[t] = (lab[t] == t) ? 1 : 0;
  __syncthreads();
  for (int off = 1; off < 512; off <<= 1) {
    int v = (t >= off) ? ids[t - off] : 0;
    __syncthreads();
    ids[t] += v;
    __syncthreads();
  }
  comp[b * NN + t] = ids[lab[t]];
  maskF[b * NN + t] = (t < ids[511]) ? 1.0f : 0.0f;
}

// ---------- segment sum x_new ----------
__global__ __launch_bounds__(256) void xnew_kernel(const float* __restrict__ H,
                                                   const int* __restrict__ comp,
                                                   float* __restrict__ xnew) {
  int i = blockIdx.x, b = blockIdx.y, f = threadIdx.x;
  int s = comp[b * NN + i] - 1;
  atomicAdd(&xnew[((size_t)(b * NN + s)) * FF + f], H[((size_t)(b * NN + i)) * FF + f]);
}

// ---------- adj_new from adjbits (adj in {0,1}) ----------
__global__ __launch_bounds__(64) void adjnew_kernel(const unsigned long long* __restrict__ adjbits,
                                                    const int* __restrict__ comp,
                                                    float* __restrict__ out) {
  int b = blockIdx.y, lane = threadIdx.x;
  int i = blockIdx.x * 8 + (lane >> 3);
  int q = lane & 7;
  unsigned long long bits = adjbits[((size_t)(b * NN + i)) * 8 + q];
  if (!bits) return;
  int si = comp[b * NN + i] - 1;
  float* ob = out + (size_t)b * NN * NN;
  while (bits) {
    int j = (q << 6) + __builtin_ctzll(bits);
    bits &= bits - 1;
    int sj = comp[b * NN + j] - 1;
    ob[(size_t)si * NN + sj] = 1.0f;  // all writers write 1.0 -> benign race
  }
}

extern "C" void kernel_launch(void* const* d_in, const int* in_sizes, int n_in,
                              void* d_out, int out_size, void* d_ws, size_t ws_size,
                              hipStream_t stream) {
  (void)in_sizes; (void)n_in; (void)out_size; (void)ws_size;
  const float* x   = (const float*)d_in[0];
  const float* adj = (const float*)d_in[1];
  const float* W1 = (const float*)d_in[3];
  const float* b1 = (const float*)d_in[4];
  const float* W2 = (const float*)d_in[5];
  const float* b2 = (const float*)d_in[6];

  float* out = (float*)d_out;
  float* xnew      = out;                       // 2097152 f
  float* adjnew    = out + 2097152;             // 4194304 f
  float* conceptsF = out + 6291456;             // 8192 f
  float* hout      = out + 6299648;             // 2097152 f
  float* maskF     = out + 8396800;             // 8192 f

  char* ws = (char*)d_ws;
  double* dinv = (double*)(ws + 0);                    // 64 KB
  float*  y    = (float*)(ws + 65536);                 // 8 MB, ends 8454144
  float*  h1   = (float*)(ws + 8454144);               // 8 MB, ends 16842752
  // kmeans buffers overlay h1 region (h1 dead after gemm2; zeroed in spmv2):
  double* centprev = (double*)(ws + 8454144);          // 11*32*256 d = 720896 -> 9175040
  double* cent_sum = (double*)(ws + 9175040);          // 720896 -> 9895936
  int*    cntI     = (int*)(ws + 9895936);             // 1408 (+zero overrun ok inside h1 region)
  double* cent0 = (double*)(ws + 16842752);            // 64 KB
  double* p2    = (double*)(ws + 16908544);            // 64 KB
  unsigned long long* adjbits = (unsigned long long*)(ws + 16974080);  // 512 KB -> 17498368
  int* assignI = (int*)(ws + 17498368);                // 32 KB (aliased as degv early)
  int* comp    = (int*)(ws + 17531136);                // 32 KB -> 17563904
  int* degv    = assignI;  // degv dead before assignI's first write (kmeans starts after spmv2)
  unsigned short* nbr = (unsigned short*)xnew;         // 1.5 MB in xnew region (pre-memset)

  // adj_new no longer used as scratch -> zero it first (overlaps later work in-graph)
  hipMemsetAsync(adjnew, 0, (size_t)4194304 * sizeof(float), stream);

  // one pass over adj: bits + neighbor lists + normalization
  build_adjbits<<<dim3(NN, BB), 64, 0, stream>>>(adj, adjbits, dinv, nbr, degv);

  // GCN layer 1 and 2 (spmv2 also emits p2/cent0 and zeroes kmeans buffers)
  gemm_scale<<<dim3(8, 4, BB), 256, 0, stream>>>(x, W1, dinv, y);
  spmv_relu<<<dim3(NN, BB), 256, 0, stream>>>(y, nbr, degv, adjbits, dinv, b1, h1,
                                              nullptr, nullptr, nullptr);
  gemm_scale<<<dim3(8, 4, BB), 256, 0, stream>>>(h1, W2, dinv, y);
  spmv_relu<<<dim3(NN, BB), 256, 0, stream>>>(y, nbr, degv, adjbits, dinv, b2, hout,
                                              p2, cent0, (char*)centprev);

  // nbr (in xnew region) now dead -> zero x_new
  hipMemsetAsync(xnew, 0, (size_t)2097152 * sizeof(float), stream);

  // kmeans: 11 launches, update folded into next assign via atomic partial sums
  const float* pts = hout;
  for (int it = 0; it <= KITERS; ++it) {
    kmeans_it<<<256, 256, 0, stream>>>(pts, cent0, centprev, cent_sum, cntI, p2,
                                       assignI, (it == KITERS) ? conceptsF : nullptr, it);
  }

  // connected components (build_bits inlined)
  components_kernel<<<BB, 512, 0, stream>>>(adjbits, assignI, comp, maskF);

  // segment reductions
  xnew_kernel<<<dim3(NN, BB), 256, 0, stream>>>(hout, comp, xnew);
  adjnew_kernel<<<dim3(64, BB), 64, 0, stream>>>(adjbits, comp, adjnew);
}